// Round 9
// baseline (147.678 us; speedup 1.0000x reference)
//
#include <hip/hip_runtime.h>
#include <stdint.h>

// MLA attention, MI355X round 9.
// Stage 1: kv = compressed_kv @ w_up^T  (bf16 MFMA, m97-style 128x128 tile)
// Stage 2: causal flash attention, 8-wave swapped-QK^T 32x32x16 (r8 inner loop):
//   wave = (k-half 0/1) x (q-strip 0..3); q-tile 128, KV tile 64.
//   K-rope in registers (dbuf prefetch); LDS 65K/block (Kn dbuf + Vt dbuf)
//   -> 2 blocks/CU (133K of 160K), 16 waves/CU at VGPR=128.
//   r9: parity-complement qt map — adjacent bids (2i,2i+1) get (u, 7-u) and the
//   SAME bh, so co-located pairs sum to 18 KV64-units on every CU regardless of
//   which qt; fixes r8's same-qt adjacent pairing (heavy CUs did 32 units).
// NOTE: __launch_bounds__ 2nd arg = min BLOCKS per CU on this toolchain.

#define Hz 16
#define Sz 1024
#define RANKz 512
#define SCALEf 0.07216878364870323f
#define CRr(r) ((((r) & 3)) + 8 * ((r) >> 2) + 4 * hi)

typedef unsigned short u16;
typedef __attribute__((ext_vector_type(8))) short bf16x8;
typedef __attribute__((ext_vector_type(4))) float f32x4;
typedef __attribute__((ext_vector_type(16))) float f32x16;

__device__ __forceinline__ u16 f2b(float f) {
  union { float f; uint32_t u; } x; x.f = f;
  return (u16)((x.u + 0x7fffu + ((x.u >> 16) & 1u)) >> 16);
}
__device__ __forceinline__ uint32_t cvtpk(float lo, float hi_) {
  uint32_t r;
  asm("v_cvt_pk_bf16_f32 %0, %1, %2" : "=v"(r) : "v"(lo), "v"(hi_));
  return r;
}

// ---------------------------------------------------------------- cvt fp32->bf16
__global__ void cvt_bf16_kernel(const float* __restrict__ a, u16* __restrict__ ao,
                                const float* __restrict__ b, u16* __restrict__ bo,
                                const float* __restrict__ c, u16* __restrict__ co,
                                int na, int nb) {
  int idx = blockIdx.x * blockDim.x + threadIdx.x;
  const float* s; u16* d; int i;
  if (idx < na)            { s = a; d = ao; i = idx; }
  else if (idx < na + nb)  { s = b; d = bo; i = idx - na; }
  else                     { s = c; d = co; i = idx - na - nb; }
  float4 v = ((const float4*)s)[i];
  ushort4 o = make_ushort4(f2b(v.x), f2b(v.y), f2b(v.z), f2b(v.w));
  ((ushort4*)d)[i] = o;
}

// ---------------------------------------------------------------- stage 1 GEMM
__global__ __launch_bounds__(256)
void gemm_kv_bf16(const u16* __restrict__ A,
                  const u16* __restrict__ Bm,
                  u16* __restrict__ C) {
  __shared__ u16 As[128 * 32];
  __shared__ u16 Bs[128 * 32];
  const int tid = threadIdx.x;
  const int w = tid >> 6, lane = tid & 63;
  const int wr = w >> 1, wc = w & 1;
  const int row0 = blockIdx.x * 128, col0 = blockIdx.y * 128;
  f32x4 acc[4][4];
#pragma unroll
  for (int m = 0; m < 4; ++m)
#pragma unroll
    for (int n = 0; n < 4; ++n) acc[m][n] = (f32x4){0.f, 0.f, 0.f, 0.f};

  const int rstage = (lane >> 2);
  const int cstage = (lane & 3) * 8;

  for (int kt = 0; kt < RANKz / 32; ++kt) {
    const int k0 = kt * 32;
#pragma unroll
    for (int i = 0; i < 2; ++i) {
      const int chunk = i * 4 + w;
      const int r = chunk * 16 + rstage;
      const u16* ga = A  + (size_t)(row0 + r) * RANKz + k0 + cstage;
      const u16* gb = Bm + (size_t)(col0 + r) * RANKz + k0 + cstage;
      __builtin_amdgcn_global_load_lds((const __attribute__((address_space(1))) void*)ga,
                                       (__attribute__((address_space(3))) void*)&As[chunk * 512], 16, 0, 0);
      __builtin_amdgcn_global_load_lds((const __attribute__((address_space(1))) void*)gb,
                                       (__attribute__((address_space(3))) void*)&Bs[chunk * 512], 16, 0, 0);
    }
    __syncthreads();
    const int klo = (lane >> 4) * 8;
    bf16x8 af[4], bfr[4];
#pragma unroll
    for (int m = 0; m < 4; ++m)
      af[m] = *(const bf16x8*)&As[(wr * 64 + m * 16 + (lane & 15)) * 32 + klo];
#pragma unroll
    for (int n = 0; n < 4; ++n)
      bfr[n] = *(const bf16x8*)&Bs[(wc * 64 + n * 16 + (lane & 15)) * 32 + klo];
#pragma unroll
    for (int m = 0; m < 4; ++m)
#pragma unroll
      for (int n = 0; n < 4; ++n)
        acc[m][n] = __builtin_amdgcn_mfma_f32_16x16x32_bf16(af[m], bfr[n], acc[m][n], 0, 0, 0);
    __syncthreads();
  }
  const int cb = col0 + wc * 64 + (lane & 15);
  const int rb = row0 + wr * 64 + (lane >> 4) * 4;
#pragma unroll
  for (int m = 0; m < 4; ++m)
#pragma unroll
    for (int n = 0; n < 4; ++n)
#pragma unroll
      for (int j = 0; j < 4; ++j)
        C[(size_t)(rb + m * 16 + j) * 4096 + (cb + n * 16)] = f2b(acc[m][n][j]);
}

// ---------------------------------------------------------------- stage 2: attention
// LDS map (66560/block): Kn dbuf @0 (2x16K), Vt dbuf @32768 (2x16K).
// Merge overlay after last tile: mb fp32 @0 (64K), ml @65536 (1K).
__global__ __launch_bounds__(512, 2)
void mla_attn_mfma(const float* __restrict__ q,
                   const u16* __restrict__ kvb,     // [T][16][256] bf16
                   const u16* __restrict__ ropeb,   // [T][64] bf16
                   float* __restrict__ out) {       // [T][16][128] fp32
  __shared__ __align__(16) unsigned char LB[66560];

  const int tid = threadIdx.x;
  const int w = tid >> 6, lane = tid & 63;
  const int l31 = lane & 31, hi = lane >> 5;
  const int half = w >> 2, strip = w & 3;

  // r9: parity-complement mapping. Adjacent bids (2i, 2i+1) -> same bh,
  // complementary qt (u, 7-u): any adjacent co-location is load-balanced.
  const int bid = blockIdx.x;
  const int ip = bid >> 1;
  const int u = ip & 3;
  const int qt = (bid & 1) ? (7 - u) : u;
  const int bh = ip >> 2;                          // 0..63
  const int bat = bh >> 4, h = bh & 15;
  const int tok0 = bat * Sz;
  const int q0 = qt * 128 + strip * 32;            // wave strip's q base (in-batch)
  const int ntiles = 2 * qt + 2;

  const int vkp = tid & 31, vdc = tid >> 5;        // V stage: k-pair 0..31, d-chunk8 0..15
  uint4 va, vb;
  bf16x8 krc[4], krr[4];                           // K-rope cur / next (regs)

  auto stageK = [&](int tokt, int buf) {
#pragma unroll
    for (int i = 0; i < 2; ++i) {                  // Kn: 16 chunks of 1KB
      const int c = w * 2 + i;
      const int row = c * 4 + (lane >> 4);
      const int sc = (lane & 15) ^ (row & 7);
      const u16* src = kvb + ((size_t)(tokt + row) * Hz + h) * 256 + sc * 8;
      __builtin_amdgcn_global_load_lds((const __attribute__((address_space(1))) void*)src,
                                       (__attribute__((address_space(3))) void*)(LB + buf * 16384 + c * 1024), 16, 0, 0);
    }
  };
  auto loadV = [&](int tokt) {
    const u16* vp = kvb + ((size_t)(tokt + vkp * 2) * Hz + h) * 256 + 128 + vdc * 8;
    va = *(const uint4*)vp;                        // token 2*vkp,   d vdc*8..+7
    vb = *(const uint4*)(vp + Hz * 256);           // token 2*vkp+1
  };
  auto writeVt = [&](int buf) {
    union { uint4 v; u16 u[8]; } A_, B_;
    A_.v = va; B_.v = vb;
    uint32_t* vt = (uint32_t*)(LB + 32768 + buf * 16384);
#pragma unroll
    for (int i = 0; i < 8; ++i) {
      const int d = vdc * 8 + i;
      vt[d * 32 + 4 * ((vkp >> 2) ^ (d & 7)) + (vkp & 3)] =
          (uint32_t)A_.u[i] | ((uint32_t)B_.u[i] << 16);
    }
  };
  auto loadRope = [&](int tokt, bf16x8* kr) {      // row = half*32+l31, frag j: +16j+8hi
    const u16* rp = ropeb + (size_t)(tokt + half * 32 + l31) * 64 + hi * 8;
#pragma unroll
    for (int j = 0; j < 4; ++j) kr[j] = *(const bf16x8*)(rp + j * 16);
  };

  // ---- Q fragments (B-operand), prescaled by SCALE
  bf16x8 qf[12];
  {
    const float* qp = q + ((size_t)(tok0 + q0 + l31) * Hz + h) * 192 + hi * 8;
#pragma unroll
    for (int ds = 0; ds < 12; ++ds) {
      float4 a = *(const float4*)(qp + ds * 16);
      float4 b = *(const float4*)(qp + ds * 16 + 4);
      union { bf16x8 v; u16 u[8]; } t;
      t.u[0] = f2b(a.x * SCALEf); t.u[1] = f2b(a.y * SCALEf);
      t.u[2] = f2b(a.z * SCALEf); t.u[3] = f2b(a.w * SCALEf);
      t.u[4] = f2b(b.x * SCALEf); t.u[5] = f2b(b.y * SCALEf);
      t.u[6] = f2b(b.z * SCALEf); t.u[7] = f2b(b.w * SCALEf);
      qf[ds] = t.v;
    }
  }

  f32x16 acc[4];
#pragma unroll
  for (int db = 0; db < 4; ++db)
#pragma unroll
    for (int r = 0; r < 16; ++r) acc[db][r] = 0.f;
  float m_run = -1e30f, l_run = 0.f;

  // ---- prologue: stage tile 0
  loadRope(tok0, krc);
  stageK(tok0, 0);
  loadV(tok0);
  __syncthreads();
  writeVt(0);
  __syncthreads();

#pragma unroll 1
  for (int t = 0; t < ntiles; ++t) {
    const int cur = t & 1;
    const bool havenext = (t + 1 < ntiles);
    if (havenext) {
      stageK(tok0 + (t + 1) * 64, cur ^ 1);
      loadV(tok0 + (t + 1) * 64);
      loadRope(tok0 + (t + 1) * 64, krr);
    }

    const int kb = t * 64 + half * 32;             // wave's k base this tile
    if (kb <= q0 + 31) {                           // wave-active
      const u16* KnC = (const u16*)(LB + cur * 16384);
      const int row_a = half * 32 + l31;
      const int swz = row_a & 7;

      f32x16 s0;
#pragma unroll
      for (int r = 0; r < 16; ++r) s0[r] = 0.f;
      __builtin_amdgcn_s_setprio(1);
#pragma unroll
      for (int ds = 0; ds < 8; ++ds) {
        bf16x8 kf = *(const bf16x8*)&KnC[row_a * 128 + 8 * ((2 * ds + hi) ^ swz)];
        s0 = __builtin_amdgcn_mfma_f32_32x32x16_bf16(kf, qf[ds], s0, 0, 0, 0);
      }
#pragma unroll
      for (int j = 0; j < 4; ++j)
        s0 = __builtin_amdgcn_mfma_f32_32x32x16_bf16(krc[j], qf[8 + j], s0, 0, 0, 0);
      __builtin_amdgcn_s_setprio(0);

      // ---- causal mask (edge sub-tiles only)
      if (kb + 31 > q0) {
#pragma unroll
        for (int r = 0; r < 16; ++r)
          if (kb + CRr(r) > q0 + l31) s0[r] = -1e30f;
      }

      // ---- in-register online softmax (lane owns q-col l31), defer-max THR=8
      float mx = s0[0];
#pragma unroll
      for (int r = 1; r < 16; ++r) mx = fmaxf(mx, s0[r]);
      mx = fmaxf(mx, __shfl_xor(mx, 32));
      if (__any(mx > m_run + 8.f)) {
        const float nm = fmaxf(m_run, mx);
        const float cr = __expf(m_run - nm);
        m_run = nm; l_run *= cr;
#pragma unroll
        for (int r = 0; r < 16; ++r) {
          const float crg = __shfl(cr, CRr(r));
#pragma unroll
          for (int db = 0; db < 4; ++db) acc[db][r] *= crg;
        }
      }
      float ts = 0.f;
#pragma unroll
      for (int r = 0; r < 16; ++r) { s0[r] = __expf(s0[r] - m_run); ts += s0[r]; }
      ts += __shfl_xor(ts, 32);
      l_run += ts;

      // ---- P -> A-frags: cvt_pk + xor-32 word swap
      bf16x8 pf[2];
#pragma unroll
      for (int ks = 0; ks < 2; ++ks) {
        const int o = ks * 8;
        const uint32_t w0 = cvtpk(s0[o + 0], s0[o + 1]);
        const uint32_t w1 = cvtpk(s0[o + 4], s0[o + 5]);
        const uint32_t w2 = cvtpk(s0[o + 2], s0[o + 3]);
        const uint32_t w3 = cvtpk(s0[o + 6], s0[o + 7]);
        const uint32_t t0 = __shfl_xor(w0, 32), t1 = __shfl_xor(w1, 32);
        const uint32_t t2 = __shfl_xor(w2, 32), t3 = __shfl_xor(w3, 32);
        union { bf16x8 v; uint32_t u[4]; } P;
        P.u[0] = hi ? t1 : w0;
        P.u[1] = hi ? t3 : w2;
        P.u[2] = hi ? w1 : t0;
        P.u[3] = hi ? w3 : t2;
        pf[ks] = P.v;
      }

      // ---- PV: O[32q x 128d] += P[32q x 32k] * V[32k x 128d]
      const u16* VtC = (const u16*)(LB + 32768 + cur * 16384);
      __builtin_amdgcn_s_setprio(1);
#pragma unroll
      for (int ks = 0; ks < 2; ++ks)
#pragma unroll
        for (int db = 0; db < 4; ++db) {
          const int d = db * 32 + l31;
          bf16x8 vf = *(const bf16x8*)&VtC[d * 64 + 8 * ((half * 4 + 2 * ks + hi) ^ (d & 7))];
          acc[db] = __builtin_amdgcn_mfma_f32_32x32x16_bf16(pf[ks], vf, acc[db], 0, 0, 0);
        }
      __builtin_amdgcn_s_setprio(0);
    }

    if (havenext) writeVt(cur ^ 1);   // Vt[cur^1] not read this tile: safe pre-barrier
    __syncthreads();                  // publishes K(t+1)+Vt(t+1); all reads of t done
    if (havenext) {
#pragma unroll
      for (int j = 0; j < 4; ++j) krc[j] = krr[j];
    }
  }

  // ---- merge the two k-halves (fp32 partials through LDS), write out
  float* mb = (float*)LB;             // 64K (overlays Kn/Vt — reads done)
  float* ml = (float*)(LB + 65536);   // 1K
  if (half == 1) {
#pragma unroll
    for (int db = 0; db < 4; ++db)
#pragma unroll
      for (int g = 0; g < 4; ++g) {
        float4 v = make_float4(acc[db][g * 4 + 0], acc[db][g * 4 + 1],
                               acc[db][g * 4 + 2], acc[db][g * 4 + 3]);
        *(float4*)&mb[strip * 4096 + db * 1024 + g * 256 + lane * 4] = v;
      }
    if (lane < 32) { ml[strip * 64 + lane] = m_run; ml[strip * 64 + 32 + lane] = l_run; }
  }
  __syncthreads();
  if (half == 0) {
    const float mp = ml[strip * 64 + l31];
    const float lp = ml[strip * 64 + 32 + l31];
    const float M  = fmaxf(m_run, mp);
    const float sA = __expf(m_run - M);
    const float sB = __expf(mp - M);
    const float inv = 1.0f / (l_run * sA + lp * sB);
    const float fAl = sA * inv, fBl = sB * inv;
    float fA[16], fB[16];
#pragma unroll
    for (int r = 0; r < 16; ++r) { fA[r] = __shfl(fAl, CRr(r)); fB[r] = __shfl(fBl, CRr(r)); }
#pragma unroll
    for (int db = 0; db < 4; ++db)
#pragma unroll
      for (int g = 0; g < 4; ++g) {
        float4 pv = *(const float4*)&mb[strip * 4096 + db * 1024 + g * 256 + lane * 4];
#pragma unroll
        for (int jj = 0; jj < 4; ++jj) {
          const int r = g * 4 + jj;
          const float pvj = (jj == 0) ? pv.x : (jj == 1) ? pv.y : (jj == 2) ? pv.z : pv.w;
          out[((size_t)(tok0 + q0 + CRr(r)) * Hz + h) * 128 + db * 32 + l31] =
              acc[db][r] * fA[r] + pvj * fB[r];
        }
      }
  }
}

// ---------------------------------------------------------------- launch
extern "C" void kernel_launch(void* const* d_in, const int* in_sizes, int n_in,
                              void* d_out, int out_size, void* d_ws, size_t ws_size,
                              hipStream_t stream) {
  const float* q    = (const float*)d_in[0];
  const float* ckv  = (const float*)d_in[1];
  const float* rope = (const float*)d_in[2];
  const float* wup  = (const float*)d_in[3];
  float* out = (float*)d_out;

  u16* ckvb  = (u16*)d_ws;
  u16* wupb  = ckvb + (size_t)4096 * RANKz;
  u16* kvb   = wupb + (size_t)4096 * RANKz;
  u16* ropeb = kvb + (size_t)4096 * 4096;

  const int nvec = 4096 * RANKz / 4;       // 524288 float4 per matrix
  const int nrope = 4096 * 64 / 4;         // 65536 float4
  cvt_bf16_kernel<<<(2 * nvec + nrope) / 256, 256, 0, stream>>>(ckv, ckvb, wup, wupb, rope, ropeb, nvec, nvec);

  dim3 gg(32, 32);
  gemm_kv_bf16<<<gg, 256, 0, stream>>>(ckvb, wupb, kvb);

  mla_attn_mfma<<<512, 512, 0, stream>>>(q, kvb, ropeb, out);
}

// Round 10
// 124.454 us; speedup vs baseline: 1.1866x; 1.1866x over previous
//
#include <hip/hip_runtime.h>
#include <stdint.h>

// MLA attention, MI355X round 10.
// Stage 1: kv = compressed_kv @ w_up^T  (bf16 MFMA, m97-style 128x128 tile)
// Stage 2: causal flash attention, 8-wave swapped-QK^T 32x32x16 (r8 inner loop)
//   + r10: per-XCD dynamic work queues (8 atomic counters, heavy-first jobs).
//   Queue x (= bid&7, round-robin XCD) owns bh in [8x, 8x+8) -> KV L2-resident.
//   Placement-proof load balance: light blocks pull extra jobs dynamically.
// NOTE: __launch_bounds__ 2nd arg = min BLOCKS per CU on this toolchain.

#define Hz 16
#define Sz 1024
#define RANKz 512
#define SCALEf 0.07216878364870323f
#define CRr(r) ((((r) & 3)) + 8 * ((r) >> 2) + 4 * hi)

typedef unsigned short u16;
typedef __attribute__((ext_vector_type(8))) short bf16x8;
typedef __attribute__((ext_vector_type(4))) float f32x4;
typedef __attribute__((ext_vector_type(16))) float f32x16;

__device__ __forceinline__ u16 f2b(float f) {
  union { float f; uint32_t u; } x; x.f = f;
  return (u16)((x.u + 0x7fffu + ((x.u >> 16) & 1u)) >> 16);
}
__device__ __forceinline__ uint32_t cvtpk(float lo, float hi_) {
  uint32_t r;
  asm("v_cvt_pk_bf16_f32 %0, %1, %2" : "=v"(r) : "v"(lo), "v"(hi_));
  return r;
}

// ---------------------------------------------------------------- cvt fp32->bf16
__global__ void cvt_bf16_kernel(const float* __restrict__ a, u16* __restrict__ ao,
                                const float* __restrict__ b, u16* __restrict__ bo,
                                const float* __restrict__ c, u16* __restrict__ co,
                                int na, int nb) {
  int idx = blockIdx.x * blockDim.x + threadIdx.x;
  const float* s; u16* d; int i;
  if (idx < na)            { s = a; d = ao; i = idx; }
  else if (idx < na + nb)  { s = b; d = bo; i = idx - na; }
  else                     { s = c; d = co; i = idx - na - nb; }
  float4 v = ((const float4*)s)[i];
  ushort4 o = make_ushort4(f2b(v.x), f2b(v.y), f2b(v.z), f2b(v.w));
  ((ushort4*)d)[i] = o;
}

// ---------------------------------------------------------------- stage 1 GEMM
__global__ __launch_bounds__(256)
void gemm_kv_bf16(const u16* __restrict__ A,
                  const u16* __restrict__ Bm,
                  u16* __restrict__ C) {
  __shared__ u16 As[128 * 32];
  __shared__ u16 Bs[128 * 32];
  const int tid = threadIdx.x;
  const int w = tid >> 6, lane = tid & 63;
  const int wr = w >> 1, wc = w & 1;
  const int row0 = blockIdx.x * 128, col0 = blockIdx.y * 128;
  f32x4 acc[4][4];
#pragma unroll
  for (int m = 0; m < 4; ++m)
#pragma unroll
    for (int n = 0; n < 4; ++n) acc[m][n] = (f32x4){0.f, 0.f, 0.f, 0.f};

  const int rstage = (lane >> 2);
  const int cstage = (lane & 3) * 8;

  for (int kt = 0; kt < RANKz / 32; ++kt) {
    const int k0 = kt * 32;
#pragma unroll
    for (int i = 0; i < 2; ++i) {
      const int chunk = i * 4 + w;
      const int r = chunk * 16 + rstage;
      const u16* ga = A  + (size_t)(row0 + r) * RANKz + k0 + cstage;
      const u16* gb = Bm + (size_t)(col0 + r) * RANKz + k0 + cstage;
      __builtin_amdgcn_global_load_lds((const __attribute__((address_space(1))) void*)ga,
                                       (__attribute__((address_space(3))) void*)&As[chunk * 512], 16, 0, 0);
      __builtin_amdgcn_global_load_lds((const __attribute__((address_space(1))) void*)gb,
                                       (__attribute__((address_space(3))) void*)&Bs[chunk * 512], 16, 0, 0);
    }
    __syncthreads();
    const int klo = (lane >> 4) * 8;
    bf16x8 af[4], bfr[4];
#pragma unroll
    for (int m = 0; m < 4; ++m)
      af[m] = *(const bf16x8*)&As[(wr * 64 + m * 16 + (lane & 15)) * 32 + klo];
#pragma unroll
    for (int n = 0; n < 4; ++n)
      bfr[n] = *(const bf16x8*)&Bs[(wc * 64 + n * 16 + (lane & 15)) * 32 + klo];
#pragma unroll
    for (int m = 0; m < 4; ++m)
#pragma unroll
      for (int n = 0; n < 4; ++n)
        acc[m][n] = __builtin_amdgcn_mfma_f32_16x16x32_bf16(af[m], bfr[n], acc[m][n], 0, 0, 0);
    __syncthreads();
  }
  const int cb = col0 + wc * 64 + (lane & 15);
  const int rb = row0 + wr * 64 + (lane >> 4) * 4;
#pragma unroll
  for (int m = 0; m < 4; ++m)
#pragma unroll
    for (int n = 0; n < 4; ++n)
#pragma unroll
      for (int j = 0; j < 4; ++j)
        C[(size_t)(rb + m * 16 + j) * 4096 + (cb + n * 16)] = f2b(acc[m][n][j]);
}

// ---------------------------------------------------------------- stage 2: attention
// LDS map (66592/block): Kn dbuf @0 (2x16K), Vt dbuf @32768 (2x16K),
// merge overlay mb @0 (64K) + ml @65536 (1K), job slot @66560.
__global__ __launch_bounds__(512, 2)
void mla_attn_mfma(const float* __restrict__ q,
                   const u16* __restrict__ kvb,     // [T][16][256] bf16
                   const u16* __restrict__ ropeb,   // [T][64] bf16
                   float* __restrict__ out,         // [T][16][128] fp32
                   int* __restrict__ jobq) {        // 8 per-XCD counters
  __shared__ __align__(16) unsigned char LB[66592];

  const int tid = threadIdx.x;
  const int w = tid >> 6, lane = tid & 63;
  const int l31 = lane & 31, hi = lane >> 5;
  const int half = w >> 2, strip = w & 3;
  const int x = blockIdx.x & 7;                    // XCD queue (round-robin assumption)

  const int vkp = tid & 31, vdc = tid >> 5;        // V stage: k-pair 0..31, d-chunk8 0..15
  volatile int* jobSlot = (volatile int*)(LB + 66560);

  for (;;) {
    // ---- pull next job (one atomic per block per job)
    if (tid == 0) *jobSlot = atomicAdd(&jobq[x], 1);
    __syncthreads();                               // publish job; fence prev merge reads
    const int j = *jobSlot;
    if (j >= 64) break;
    const int qt = 7 - (j >> 3);                   // heavy-first
    const int bh = x * 8 + (j & 7);                // queue x owns 8 heads (L2-resident)
    const int bat = bh >> 4, h = bh & 15;
    const int tok0 = bat * Sz;
    const int q0 = qt * 128 + strip * 32;
    const int ntiles = 2 * qt + 2;

    uint4 va, vb;
    bf16x8 krc[4], krr[4];

    auto stageK = [&](int tokt, int buf) {
#pragma unroll
      for (int i = 0; i < 2; ++i) {                // Kn: 16 chunks of 1KB
        const int c = w * 2 + i;
        const int row = c * 4 + (lane >> 4);
        const int sc = (lane & 15) ^ (row & 7);
        const u16* src = kvb + ((size_t)(tokt + row) * Hz + h) * 256 + sc * 8;
        __builtin_amdgcn_global_load_lds((const __attribute__((address_space(1))) void*)src,
                                         (__attribute__((address_space(3))) void*)(LB + buf * 16384 + c * 1024), 16, 0, 0);
      }
    };
    auto loadV = [&](int tokt) {
      const u16* vp = kvb + ((size_t)(tokt + vkp * 2) * Hz + h) * 256 + 128 + vdc * 8;
      va = *(const uint4*)vp;
      vb = *(const uint4*)(vp + Hz * 256);
    };
    auto writeVt = [&](int buf) {
      union { uint4 v; u16 u[8]; } A_, B_;
      A_.v = va; B_.v = vb;
      uint32_t* vt = (uint32_t*)(LB + 32768 + buf * 16384);
#pragma unroll
      for (int i = 0; i < 8; ++i) {
        const int d = vdc * 8 + i;
        vt[d * 32 + 4 * ((vkp >> 2) ^ (d & 7)) + (vkp & 3)] =
            (uint32_t)A_.u[i] | ((uint32_t)B_.u[i] << 16);
      }
    };
    auto loadRope = [&](int tokt, bf16x8* kr) {
      const u16* rp = ropeb + (size_t)(tokt + half * 32 + l31) * 64 + hi * 8;
#pragma unroll
      for (int jj = 0; jj < 4; ++jj) kr[jj] = *(const bf16x8*)(rp + jj * 16);
    };

    // ---- Q fragments (B-operand), prescaled by SCALE
    bf16x8 qf[12];
    {
      const float* qp = q + ((size_t)(tok0 + q0 + l31) * Hz + h) * 192 + hi * 8;
#pragma unroll
      for (int ds = 0; ds < 12; ++ds) {
        float4 a = *(const float4*)(qp + ds * 16);
        float4 b = *(const float4*)(qp + ds * 16 + 4);
        union { bf16x8 v; u16 u[8]; } t;
        t.u[0] = f2b(a.x * SCALEf); t.u[1] = f2b(a.y * SCALEf);
        t.u[2] = f2b(a.z * SCALEf); t.u[3] = f2b(a.w * SCALEf);
        t.u[4] = f2b(b.x * SCALEf); t.u[5] = f2b(b.y * SCALEf);
        t.u[6] = f2b(b.z * SCALEf); t.u[7] = f2b(b.w * SCALEf);
        qf[ds] = t.v;
      }
    }

    f32x16 acc[4];
#pragma unroll
    for (int db = 0; db < 4; ++db)
#pragma unroll
      for (int r = 0; r < 16; ++r) acc[db][r] = 0.f;
    float m_run = -1e30f, l_run = 0.f;

    // ---- prologue: stage tile 0 (V/rope first: their waits leave gll in flight)
    loadV(tok0);
    loadRope(tok0, krc);
    stageK(tok0, 0);
    __syncthreads();
    writeVt(0);
    __syncthreads();

#pragma unroll 1
    for (int t = 0; t < ntiles; ++t) {
      const int cur = t & 1;
      const bool havenext = (t + 1 < ntiles);
      if (havenext) {
        loadV(tok0 + (t + 1) * 64);
        loadRope(tok0 + (t + 1) * 64, krr);
        stageK(tok0 + (t + 1) * 64, cur ^ 1);
      }

      const int kb = t * 64 + half * 32;
      if (kb <= q0 + 31) {                         // wave-active
        const u16* KnC = (const u16*)(LB + cur * 16384);
        const int row_a = half * 32 + l31;
        const int swz = row_a & 7;

        f32x16 s0;
#pragma unroll
        for (int r = 0; r < 16; ++r) s0[r] = 0.f;
        __builtin_amdgcn_s_setprio(1);
#pragma unroll
        for (int ds = 0; ds < 8; ++ds) {
          bf16x8 kf = *(const bf16x8*)&KnC[row_a * 128 + 8 * ((2 * ds + hi) ^ swz)];
          s0 = __builtin_amdgcn_mfma_f32_32x32x16_bf16(kf, qf[ds], s0, 0, 0, 0);
        }
#pragma unroll
        for (int jj = 0; jj < 4; ++jj)
          s0 = __builtin_amdgcn_mfma_f32_32x32x16_bf16(krc[jj], qf[8 + jj], s0, 0, 0, 0);
        __builtin_amdgcn_s_setprio(0);

        // ---- causal mask (edge sub-tiles only)
        if (kb + 31 > q0) {
#pragma unroll
          for (int r = 0; r < 16; ++r)
            if (kb + CRr(r) > q0 + l31) s0[r] = -1e30f;
        }

        // ---- in-register online softmax, tree max, defer-max THR=8
        float ma0 = fmaxf(s0[0], s0[1]),   ma1 = fmaxf(s0[2], s0[3]);
        float ma2 = fmaxf(s0[4], s0[5]),   ma3 = fmaxf(s0[6], s0[7]);
        float ma4 = fmaxf(s0[8], s0[9]),   ma5 = fmaxf(s0[10], s0[11]);
        float ma6 = fmaxf(s0[12], s0[13]), ma7 = fmaxf(s0[14], s0[15]);
        float mx = fmaxf(fmaxf(fmaxf(ma0, ma1), fmaxf(ma2, ma3)),
                         fmaxf(fmaxf(ma4, ma5), fmaxf(ma6, ma7)));
        mx = fmaxf(mx, __shfl_xor(mx, 32));
        if (__any(mx > m_run + 8.f)) {
          const float nm = fmaxf(m_run, mx);
          const float cr = __expf(m_run - nm);
          m_run = nm; l_run *= cr;
#pragma unroll
          for (int r = 0; r < 16; ++r) {
            const float crg = __shfl(cr, CRr(r));
#pragma unroll
            for (int db = 0; db < 4; ++db) acc[db][r] *= crg;
          }
        }
        float ts = 0.f;
#pragma unroll
        for (int r = 0; r < 16; ++r) { s0[r] = __expf(s0[r] - m_run); ts += s0[r]; }
        ts += __shfl_xor(ts, 32);
        l_run += ts;

        // ---- P -> A-frags: cvt_pk + xor-32 word swap
        bf16x8 pf[2];
#pragma unroll
        for (int ks = 0; ks < 2; ++ks) {
          const int o = ks * 8;
          const uint32_t w0 = cvtpk(s0[o + 0], s0[o + 1]);
          const uint32_t w1 = cvtpk(s0[o + 4], s0[o + 5]);
          const uint32_t w2 = cvtpk(s0[o + 2], s0[o + 3]);
          const uint32_t w3 = cvtpk(s0[o + 6], s0[o + 7]);
          const uint32_t t0 = __shfl_xor(w0, 32), t1 = __shfl_xor(w1, 32);
          const uint32_t t2 = __shfl_xor(w2, 32), t3 = __shfl_xor(w3, 32);
          union { bf16x8 v; uint32_t u[4]; } P;
          P.u[0] = hi ? t1 : w0;
          P.u[1] = hi ? t3 : w2;
          P.u[2] = hi ? w1 : t0;
          P.u[3] = hi ? w3 : t2;
          pf[ks] = P.v;
        }

        // ---- PV: O[32q x 128d] += P[32q x 32k] * V[32k x 128d]
        const u16* VtC = (const u16*)(LB + 32768 + cur * 16384);
        __builtin_amdgcn_s_setprio(1);
#pragma unroll
        for (int ks = 0; ks < 2; ++ks)
#pragma unroll
          for (int db = 0; db < 4; ++db) {
            const int d = db * 32 + l31;
            bf16x8 vf = *(const bf16x8*)&VtC[d * 64 + 8 * ((half * 4 + 2 * ks + hi) ^ (d & 7))];
            acc[db] = __builtin_amdgcn_mfma_f32_32x32x16_bf16(pf[ks], vf, acc[db], 0, 0, 0);
          }
        __builtin_amdgcn_s_setprio(0);
      }

      if (havenext) writeVt(cur ^ 1);  // Vt[cur^1] not read this tile: safe pre-barrier
      __syncthreads();                 // publishes K(t+1)+Vt(t+1); all reads of t done
      if (havenext) {
#pragma unroll
        for (int jj = 0; jj < 4; ++jj) krc[jj] = krr[jj];
      }
    }

    // ---- merge the two k-halves (fp32 partials through LDS), write out
    float* mb = (float*)LB;             // 64K (overlays Kn/Vt — reads done)
    float* ml = (float*)(LB + 65536);   // 1K
    if (half == 1) {
#pragma unroll
      for (int db = 0; db < 4; ++db)
#pragma unroll
        for (int g = 0; g < 4; ++g) {
          float4 v = make_float4(acc[db][g * 4 + 0], acc[db][g * 4 + 1],
                                 acc[db][g * 4 + 2], acc[db][g * 4 + 3]);
          *(float4*)&mb[strip * 4096 + db * 1024 + g * 256 + lane * 4] = v;
        }
      if (lane < 32) { ml[strip * 64 + lane] = m_run; ml[strip * 64 + 32 + lane] = l_run; }
    }
    __syncthreads();
    if (half == 0) {
      const float mp = ml[strip * 64 + l31];
      const float lp = ml[strip * 64 + 32 + l31];
      const float M  = fmaxf(m_run, mp);
      const float sA = __expf(m_run - M);
      const float sB = __expf(mp - M);
      const float inv = 1.0f / (l_run * sA + lp * sB);
      const float fAl = sA * inv, fBl = sB * inv;
      float fA[16], fB[16];
#pragma unroll
      for (int r = 0; r < 16; ++r) { fA[r] = __shfl(fAl, CRr(r)); fB[r] = __shfl(fBl, CRr(r)); }
#pragma unroll
      for (int db = 0; db < 4; ++db)
#pragma unroll
        for (int g = 0; g < 4; ++g) {
          float4 pv = *(const float4*)&mb[strip * 4096 + db * 1024 + g * 256 + lane * 4];
#pragma unroll
          for (int jj = 0; jj < 4; ++jj) {
            const int r = g * 4 + jj;
            const float pvj = (jj == 0) ? pv.x : (jj == 1) ? pv.y : (jj == 2) ? pv.z : pv.w;
            out[((size_t)(tok0 + q0 + CRr(r)) * Hz + h) * 128 + db * 32 + l31] =
                acc[db][r] * fA[r] + pvj * fB[r];
          }
        }
    }
    // loop-top barrier (after job pull) fences these merge reads from next job's writes
  }
}

// ---------------------------------------------------------------- launch
extern "C" void kernel_launch(void* const* d_in, const int* in_sizes, int n_in,
                              void* d_out, int out_size, void* d_ws, size_t ws_size,
                              hipStream_t stream) {
  const float* q    = (const float*)d_in[0];
  const float* ckv  = (const float*)d_in[1];
  const float* rope = (const float*)d_in[2];
  const float* wup  = (const float*)d_in[3];
  float* out = (float*)d_out;

  u16* ckvb  = (u16*)d_ws;
  u16* wupb  = ckvb + (size_t)4096 * RANKz;
  u16* kvb   = wupb + (size_t)4096 * RANKz;
  u16* ropeb = kvb + (size_t)4096 * 4096;
  int* jq    = (int*)(ropeb + (size_t)4096 * 64);  // 8 per-XCD job counters

  hipMemsetAsync(jq, 0, 8 * sizeof(int), stream);

  const int nvec = 4096 * RANKz / 4;       // 524288 float4 per matrix
  const int nrope = 4096 * 64 / 4;         // 65536 float4
  cvt_bf16_kernel<<<(2 * nvec + nrope) / 256, 256, 0, stream>>>(ckv, ckvb, wup, wupb, rope, ropeb, nvec, nvec);

  dim3 gg(32, 32);
  gemm_kv_bf16<<<gg, 256, 0, stream>>>(ckvb, wupb, kvb);

  mla_attn_mfma<<<512, 512, 0, stream>>>(q, kvb, ropeb, out, jq);
}

// Round 11
// 110.100 us; speedup vs baseline: 1.3413x; 1.1304x over previous
//
#include <hip/hip_runtime.h>
#include <stdint.h>

// MLA attention, MI355X round 11.
// Stage 1: kv = compressed_kv @ w_up^T  (bf16 MFMA, m97-style 128x128 tile)
// Stage 2: causal flash attention = round-5 structure (best measured: 65us)
//   + r11: __launch_bounds__(512,1) uncaps VGPR 128->256 (r5's (512,2) cap
//     starved regalloc: ~130 persistent regs left nothing for hoisting ds_reads,
//     exposing ~120cy LDS latency on all 40 reads/tile/wave);
//   + manual read batching: QK^T 2x(12 ds_read -> 12 MFMA), PV 2x(8 -> 8).
// 8 waves = (k-half 0/1) x (q-strip 0..3); q-tile 128, KV tile 128; grid 256;
// block = q-tile pair (7-p, p) = 9 tile-computes, XCD-chunked bh.
// NOTE: __launch_bounds__ 2nd arg = min BLOCKS per CU on this toolchain.

#define Hz 16
#define Sz 1024
#define RANKz 512
#define SCALEf 0.07216878364870323f

typedef unsigned short u16;
typedef __attribute__((ext_vector_type(8))) short bf16x8;
typedef __attribute__((ext_vector_type(4))) float f32x4;
typedef __attribute__((ext_vector_type(16))) float f32x16;

__device__ __forceinline__ u16 f2b(float f) {
  union { float f; uint32_t u; } x; x.f = f;
  return (u16)((x.u + 0x7fffu + ((x.u >> 16) & 1u)) >> 16);
}
__device__ __forceinline__ uint32_t cvtpk(float lo, float hi_) {
  uint32_t r;
  asm("v_cvt_pk_bf16_f32 %0, %1, %2" : "=v"(r) : "v"(lo), "v"(hi_));
  return r;
}

// ---------------------------------------------------------------- cvt fp32->bf16
__global__ void cvt_bf16_kernel(const float* __restrict__ a, u16* __restrict__ ao,
                                const float* __restrict__ b, u16* __restrict__ bo,
                                const float* __restrict__ c, u16* __restrict__ co,
                                int na, int nb) {
  int idx = blockIdx.x * blockDim.x + threadIdx.x;
  const float* s; u16* d; int i;
  if (idx < na)            { s = a; d = ao; i = idx; }
  else if (idx < na + nb)  { s = b; d = bo; i = idx - na; }
  else                     { s = c; d = co; i = idx - na - nb; }
  float4 v = ((const float4*)s)[i];
  ushort4 o = make_ushort4(f2b(v.x), f2b(v.y), f2b(v.z), f2b(v.w));
  ((ushort4*)d)[i] = o;
}

// ---------------------------------------------------------------- stage 1 GEMM
__global__ __launch_bounds__(256)
void gemm_kv_bf16(const u16* __restrict__ A,
                  const u16* __restrict__ Bm,
                  u16* __restrict__ C) {
  __shared__ u16 As[128 * 32];
  __shared__ u16 Bs[128 * 32];
  const int tid = threadIdx.x;
  const int w = tid >> 6, lane = tid & 63;
  const int wr = w >> 1, wc = w & 1;
  const int row0 = blockIdx.x * 128, col0 = blockIdx.y * 128;
  f32x4 acc[4][4];
#pragma unroll
  for (int m = 0; m < 4; ++m)
#pragma unroll
    for (int n = 0; n < 4; ++n) acc[m][n] = (f32x4){0.f, 0.f, 0.f, 0.f};

  const int rstage = (lane >> 2);
  const int cstage = (lane & 3) * 8;

  for (int kt = 0; kt < RANKz / 32; ++kt) {
    const int k0 = kt * 32;
#pragma unroll
    for (int i = 0; i < 2; ++i) {
      const int chunk = i * 4 + w;
      const int r = chunk * 16 + rstage;
      const u16* ga = A  + (size_t)(row0 + r) * RANKz + k0 + cstage;
      const u16* gb = Bm + (size_t)(col0 + r) * RANKz + k0 + cstage;
      __builtin_amdgcn_global_load_lds((const __attribute__((address_space(1))) void*)ga,
                                       (__attribute__((address_space(3))) void*)&As[chunk * 512], 16, 0, 0);
      __builtin_amdgcn_global_load_lds((const __attribute__((address_space(1))) void*)gb,
                                       (__attribute__((address_space(3))) void*)&Bs[chunk * 512], 16, 0, 0);
    }
    __syncthreads();
    const int klo = (lane >> 4) * 8;
    bf16x8 af[4], bfr[4];
#pragma unroll
    for (int m = 0; m < 4; ++m)
      af[m] = *(const bf16x8*)&As[(wr * 64 + m * 16 + (lane & 15)) * 32 + klo];
#pragma unroll
    for (int n = 0; n < 4; ++n)
      bfr[n] = *(const bf16x8*)&Bs[(wc * 64 + n * 16 + (lane & 15)) * 32 + klo];
#pragma unroll
    for (int m = 0; m < 4; ++m)
#pragma unroll
      for (int n = 0; n < 4; ++n)
        acc[m][n] = __builtin_amdgcn_mfma_f32_16x16x32_bf16(af[m], bfr[n], acc[m][n], 0, 0, 0);
    __syncthreads();
  }
  const int cb = col0 + wc * 64 + (lane & 15);
  const int rb = row0 + wr * 64 + (lane >> 4) * 4;
#pragma unroll
  for (int m = 0; m < 4; ++m)
#pragma unroll
    for (int n = 0; n < 4; ++n)
#pragma unroll
      for (int j = 0; j < 4; ++j)
        C[(size_t)(rb + m * 16 + j) * 4096 + (cb + n * 16)] = f2b(acc[m][n][j]);
}

// ---------------------------------------------------------------- stage 2: attention
// grid 256 x 1, block 512 = 8 waves. wave = (half = w>>2, strip = w&3).
// LDS map: Kn dbuf @0 (2x32K) Kr dbuf @64K (2x16K) Vt @96K (32K). 128K total.
__global__ __launch_bounds__(512, 1)
void mla_attn_mfma(const float* __restrict__ q,
                   const u16* __restrict__ kvb,     // [T][16][256] bf16
                   const u16* __restrict__ ropeb,   // [T][64] bf16
                   float* __restrict__ out) {       // [T][16][128] fp32
  __shared__ __align__(16) unsigned char LB[131072];

  const int tid = threadIdx.x;
  const int w = tid >> 6, lane = tid & 63;
  const int l31 = lane & 31, hi = lane >> 5;
  const int half = w >> 2, strip = w & 3;

  const int bid = blockIdx.x;
  const int job = (bid & 7) * 32 + (bid >> 3);   // same-bh jobs -> same XCD
  const int bh = job >> 2, pr = job & 3;
  const int bat = bh >> 4, h = bh & 15;
  const int tok0 = bat * Sz;

  const int vkp = tid & 63, vdc = (tid >> 6) & 7;  // V stage: k-pair, d-chunk16

#pragma unroll 1
  for (int pass = 0; pass < 2; ++pass) {
    const int qt = pass ? pr : (7 - pr);
    const int ntiles = qt + 1;
    const int q0 = qt * 128 + strip * 32;         // wave's q-strip base (in-batch)

    // ---- Q fragments (B-operand), prescaled by SCALE
    bf16x8 qf[12];
    {
      const float* qp = q + ((size_t)(tok0 + q0 + l31) * Hz + h) * 192 + hi * 8;
#pragma unroll
      for (int ds = 0; ds < 12; ++ds) {
        float4 a = *(const float4*)(qp + ds * 16);
        float4 b = *(const float4*)(qp + ds * 16 + 4);
        union { bf16x8 v; u16 u[8]; } t;
        t.u[0] = f2b(a.x * SCALEf); t.u[1] = f2b(a.y * SCALEf);
        t.u[2] = f2b(a.z * SCALEf); t.u[3] = f2b(a.w * SCALEf);
        t.u[4] = f2b(b.x * SCALEf); t.u[5] = f2b(b.y * SCALEf);
        t.u[6] = f2b(b.z * SCALEf); t.u[7] = f2b(b.w * SCALEf);
        qf[ds] = t.v;
      }
    }

    f32x16 acc[4];
#pragma unroll
    for (int db = 0; db < 4; ++db)
#pragma unroll
      for (int r = 0; r < 16; ++r) acc[db][r] = 0.f;
    float m_run = -1e30f, l_run = 0.f;

    uint4 va0, va1, vb0, vb1;   // V prefetch regs (16 VGPR)

    // ---- prologue: stage tile 0 (V first: leaves gll in flight behind reg loads)
    {
      const int tokt = tok0;
      const u16* vp = kvb + ((size_t)(tokt + vkp * 2) * Hz + h) * 256 + 128 + vdc * 16;
      va0 = *(const uint4*)(vp);
      va1 = *(const uint4*)(vp + 8);
      vb0 = *(const uint4*)(vp + Hz * 256);
      vb1 = *(const uint4*)(vp + Hz * 256 + 8);
#pragma unroll
      for (int i = 0; i < 4; ++i) {              // Kn: 32 chunks of 1KB
        const int c = w * 4 + i;
        const int row = c * 4 + (lane >> 4);
        const int sc = (lane & 15) ^ (row & 7);
        const u16* src = kvb + ((size_t)(tokt + row) * Hz + h) * 256 + sc * 8;
        __builtin_amdgcn_global_load_lds((const __attribute__((address_space(1))) void*)src,
                                         (__attribute__((address_space(3))) void*)(LB + c * 1024), 16, 0, 0);
      }
#pragma unroll
      for (int i = 0; i < 2; ++i) {              // Kr: 16 chunks of 1KB
        const int c = w * 2 + i;
        const int row = c * 8 + (lane >> 3);
        const int sc = (lane & 7) ^ (row & 7);
        const u16* src = ropeb + (size_t)(tokt + row) * 64 + sc * 8;
        __builtin_amdgcn_global_load_lds((const __attribute__((address_space(1))) void*)src,
                                         (__attribute__((address_space(3))) void*)(LB + 65536 + c * 1024), 16, 0, 0);
      }
    }
    __syncthreads();
    { // write Vt(0): pack k-pairs, swizzle chunk ^= (d&7)
      union { uint4 v; u16 u[8]; } A0, A1, B0, B1;
      A0.v = va0; A1.v = va1; B0.v = vb0; B1.v = vb1;
      char* vt = (char*)(LB + 98304);
      const int inb = (4 * vkp) & 15, cc = vkp >> 2;
#pragma unroll
      for (int i = 0; i < 8; ++i) {
        { const int d = vdc * 16 + i;
          uint32_t wv = (uint32_t)A0.u[i] | ((uint32_t)B0.u[i] << 16);
          *(uint32_t*)(vt + d * 256 + 16 * (cc ^ (d & 7)) + inb) = wv; }
        { const int d = vdc * 16 + 8 + i;
          uint32_t wv = (uint32_t)A1.u[i] | ((uint32_t)B1.u[i] << 16);
          *(uint32_t*)(vt + d * 256 + 16 * (cc ^ (d & 7)) + inb) = wv; }
      }
    }
    __syncthreads();

#pragma unroll 1
    for (int t = 0; t < ntiles; ++t) {
      const int cur = t & 1;
      const bool havenext = (t + 1 < ntiles);
      if (havenext) {   // issue V(t+1) regs + gll K(t+1) into buf cur^1
        const int tokt = tok0 + (t + 1) * 128;
        const u16* vp = kvb + ((size_t)(tokt + vkp * 2) * Hz + h) * 256 + 128 + vdc * 16;
        va0 = *(const uint4*)(vp);
        va1 = *(const uint4*)(vp + 8);
        vb0 = *(const uint4*)(vp + Hz * 256);
        vb1 = *(const uint4*)(vp + Hz * 256 + 8);
#pragma unroll
        for (int i = 0; i < 4; ++i) {
          const int c = w * 4 + i;
          const int row = c * 4 + (lane >> 4);
          const int sc = (lane & 15) ^ (row & 7);
          const u16* src = kvb + ((size_t)(tokt + row) * Hz + h) * 256 + sc * 8;
          __builtin_amdgcn_global_load_lds((const __attribute__((address_space(1))) void*)src,
                                           (__attribute__((address_space(3))) void*)(LB + (cur ^ 1) * 32768 + c * 1024), 16, 0, 0);
        }
#pragma unroll
        for (int i = 0; i < 2; ++i) {
          const int c = w * 2 + i;
          const int row = c * 8 + (lane >> 3);
          const int sc = (lane & 7) ^ (row & 7);
          const u16* src = ropeb + (size_t)(tokt + row) * 64 + sc * 8;
          __builtin_amdgcn_global_load_lds((const __attribute__((address_space(1))) void*)src,
                                           (__attribute__((address_space(3))) void*)(LB + 65536 + (cur ^ 1) * 16384 + c * 1024), 16, 0, 0);
        }
      }

      const bool active = (t * 128 + half * 64) <= (q0 + 31);
      if (active) {
        const u16* KnC = (const u16*)(LB + cur * 32768);
        const u16* KrC = (const u16*)(LB + 65536 + cur * 16384);
        const int row_a = half * 64 + l31;        // kh=0 k-row
        const int row_b = row_a + 32;             // kh=1 k-row
        const int swz = row_a & 7;                // == row_b & 7

        // ---- swapped QK^T: S^T[64k x 32q]; batched reads -> batched MFMA
        f32x16 s0, s1;
#pragma unroll
        for (int r = 0; r < 16; ++r) { s0[r] = 0.f; s1[r] = 0.f; }
        bf16x8 ka[6], kb[6];
        // batch A: Kn ds = 0..5 (12 reads, then 12 MFMA)
#pragma unroll
        for (int ds = 0; ds < 6; ++ds) {
          ka[ds] = *(const bf16x8*)&KnC[row_a * 128 + 8 * ((2 * ds + hi) ^ swz)];
          kb[ds] = *(const bf16x8*)&KnC[row_b * 128 + 8 * ((2 * ds + hi) ^ swz)];
        }
        __builtin_amdgcn_s_setprio(1);
#pragma unroll
        for (int ds = 0; ds < 6; ++ds) {
          s0 = __builtin_amdgcn_mfma_f32_32x32x16_bf16(ka[ds], qf[ds], s0, 0, 0, 0);
          s1 = __builtin_amdgcn_mfma_f32_32x32x16_bf16(kb[ds], qf[ds], s1, 0, 0, 0);
        }
        __builtin_amdgcn_s_setprio(0);
        // batch B: Kn ds = 6,7 + Kr ds = 8..11
#pragma unroll
        for (int ds = 0; ds < 2; ++ds) {
          ka[ds] = *(const bf16x8*)&KnC[row_a * 128 + 8 * ((2 * (ds + 6) + hi) ^ swz)];
          kb[ds] = *(const bf16x8*)&KnC[row_b * 128 + 8 * ((2 * (ds + 6) + hi) ^ swz)];
        }
#pragma unroll
        for (int ds = 0; ds < 4; ++ds) {
          ka[2 + ds] = *(const bf16x8*)&KrC[row_a * 64 + 8 * ((2 * ds + hi) ^ swz)];
          kb[2 + ds] = *(const bf16x8*)&KrC[row_b * 64 + 8 * ((2 * ds + hi) ^ swz)];
        }
        __builtin_amdgcn_s_setprio(1);
#pragma unroll
        for (int ds = 0; ds < 6; ++ds) {
          s0 = __builtin_amdgcn_mfma_f32_32x32x16_bf16(ka[ds], qf[6 + ds], s0, 0, 0, 0);
          s1 = __builtin_amdgcn_mfma_f32_32x32x16_bf16(kb[ds], qf[6 + ds], s1, 0, 0, 0);
        }
        __builtin_amdgcn_s_setprio(0);

        // ---- causal mask (diagonal tile only)
        if (t == qt) {
          const int qg = q0 + l31;
          const int kb0 = t * 128 + half * 64;
#pragma unroll
          for (int r = 0; r < 16; ++r) {
            const int cr_ = (r & 3) + 8 * (r >> 2) + 4 * hi;
            if (kb0 + cr_ > qg)      s0[r] = -1e30f;
            if (kb0 + 32 + cr_ > qg) s1[r] = -1e30f;
          }
        }

        // ---- in-register online softmax (lane owns q-column l31), tree max
        float mp0 = fmaxf(s0[0], s0[1]),  mp1 = fmaxf(s0[2], s0[3]);
        float mp2 = fmaxf(s0[4], s0[5]),  mp3 = fmaxf(s0[6], s0[7]);
        float mp4 = fmaxf(s0[8], s0[9]),  mp5 = fmaxf(s0[10], s0[11]);
        float mp6 = fmaxf(s0[12], s0[13]), mp7 = fmaxf(s0[14], s0[15]);
        mp0 = fmaxf(mp0, fmaxf(s1[0], s1[1]));   mp1 = fmaxf(mp1, fmaxf(s1[2], s1[3]));
        mp2 = fmaxf(mp2, fmaxf(s1[4], s1[5]));   mp3 = fmaxf(mp3, fmaxf(s1[6], s1[7]));
        mp4 = fmaxf(mp4, fmaxf(s1[8], s1[9]));   mp5 = fmaxf(mp5, fmaxf(s1[10], s1[11]));
        mp6 = fmaxf(mp6, fmaxf(s1[12], s1[13])); mp7 = fmaxf(mp7, fmaxf(s1[14], s1[15]));
        float mx = fmaxf(fmaxf(fmaxf(mp0, mp1), fmaxf(mp2, mp3)),
                         fmaxf(fmaxf(mp4, mp5), fmaxf(mp6, mp7)));
        mx = fmaxf(mx, __shfl_xor(mx, 32));
        const bool need = __any(mx > m_run + 8.f);   // defer-max THR=8
        if (need) {
          const float nm = fmaxf(m_run, mx);
          const float cr = __expf(m_run - nm);
          m_run = nm; l_run *= cr;
#pragma unroll
          for (int r = 0; r < 16; ++r) {
            const float crg = __shfl(cr, (r & 3) + 8 * (r >> 2) + 4 * hi);
#pragma unroll
            for (int db = 0; db < 4; ++db) acc[db][r] *= crg;
          }
        }
        float ts = 0.f;
#pragma unroll
        for (int r = 0; r < 16; ++r) {
          s0[r] = __expf(s0[r] - m_run); ts += s0[r];
          s1[r] = __expf(s1[r] - m_run); ts += s1[r];
        }
        ts += __shfl_xor(ts, 32);
        l_run += ts;

        // ---- P -> A-frags: cvt_pk pairs + xor-32 word swap
        bf16x8 pf[4];
#pragma unroll
        for (int ks = 0; ks < 4; ++ks) {
          const int o = (ks & 1) * 8;
          uint32_t w0, w1, w2, w3;
          if (ks < 2) {
            w0 = cvtpk(s0[o + 0], s0[o + 1]); w1 = cvtpk(s0[o + 4], s0[o + 5]);
            w2 = cvtpk(s0[o + 2], s0[o + 3]); w3 = cvtpk(s0[o + 6], s0[o + 7]);
          } else {
            w0 = cvtpk(s1[o + 0], s1[o + 1]); w1 = cvtpk(s1[o + 4], s1[o + 5]);
            w2 = cvtpk(s1[o + 2], s1[o + 3]); w3 = cvtpk(s1[o + 6], s1[o + 7]);
          }
          const uint32_t t0 = __shfl_xor(w0, 32), t1 = __shfl_xor(w1, 32);
          const uint32_t t2 = __shfl_xor(w2, 32), t3 = __shfl_xor(w3, 32);
          union { bf16x8 v; uint32_t u[4]; } P;
          P.u[0] = hi ? t1 : w0;    // j=0,1
          P.u[1] = hi ? t3 : w2;    // j=2,3
          P.u[2] = hi ? w1 : t0;    // j=4,5
          P.u[3] = hi ? w3 : t2;    // j=6,7
          pf[ks] = P.v;
        }

        // ---- PV: O[32q x 128d] += P[32q x 64k] * V[64k x 128d]; batched reads
        const u16* VtC = (const u16*)(LB + 98304);
        bf16x8 vfr[8];
#pragma unroll
        for (int ks = 0; ks < 2; ++ks)
#pragma unroll
          for (int db = 0; db < 4; ++db) {
            const int row = db * 32 + l31;
            vfr[ks * 4 + db] = *(const bf16x8*)&VtC[row * 128 + 8 * ((half * 8 + 2 * ks + hi) ^ (row & 7))];
          }
        __builtin_amdgcn_s_setprio(1);
#pragma unroll
        for (int ks = 0; ks < 2; ++ks)
#pragma unroll
          for (int db = 0; db < 4; ++db)
            acc[db] = __builtin_amdgcn_mfma_f32_32x32x16_bf16(pf[ks], vfr[ks * 4 + db], acc[db], 0, 0, 0);
        __builtin_amdgcn_s_setprio(0);
#pragma unroll
        for (int ks = 0; ks < 2; ++ks)
#pragma unroll
          for (int db = 0; db < 4; ++db) {
            const int row = db * 32 + l31;
            vfr[ks * 4 + db] = *(const bf16x8*)&VtC[row * 128 + 8 * ((half * 8 + 2 * (ks + 2) + hi) ^ (row & 7))];
          }
        __builtin_amdgcn_s_setprio(1);
#pragma unroll
        for (int ks = 0; ks < 2; ++ks)
#pragma unroll
          for (int db = 0; db < 4; ++db)
            acc[db] = __builtin_amdgcn_mfma_f32_32x32x16_bf16(pf[ks + 2], vfr[ks * 4 + db], acc[db], 0, 0, 0);
        __builtin_amdgcn_s_setprio(0);
      }

      __syncthreads();   // A: all reads of Kn[cur]/Vt done; gll(t+1)+Vregs drained
      if (havenext) {
        union { uint4 v; u16 u[8]; } A0, A1, B0, B1;
        A0.v = va0; A1.v = va1; B0.v = vb0; B1.v = vb1;
        char* vt = (char*)(LB + 98304);
        const int inb = (4 * vkp) & 15, cc = vkp >> 2;
#pragma unroll
        for (int i = 0; i < 8; ++i) {
          { const int d = vdc * 16 + i;
            uint32_t wv = (uint32_t)A0.u[i] | ((uint32_t)B0.u[i] << 16);
            *(uint32_t*)(vt + d * 256 + 16 * (cc ^ (d & 7)) + inb) = wv; }
          { const int d = vdc * 16 + 8 + i;
            uint32_t wv = (uint32_t)A1.u[i] | ((uint32_t)B1.u[i] << 16);
            *(uint32_t*)(vt + d * 256 + 16 * (cc ^ (d & 7)) + inb) = wv; }
        }
        __syncthreads();  // B: Vt(t+1) published
      }
    }

    // ---- merge k-halves (waves w and w+4 share rows) + write out
    float* mb = (float*)LB;                 // 64KB acc buffer (Kn area, reads done)
    float* ml = (float*)(LB + 65536);       // m,l per strip
    if (half == 1) {
#pragma unroll
      for (int db = 0; db < 4; ++db)
#pragma unroll
        for (int q4 = 0; q4 < 4; ++q4) {
          float4 v = make_float4(acc[db][q4 * 4 + 0], acc[db][q4 * 4 + 1],
                                 acc[db][q4 * 4 + 2], acc[db][q4 * 4 + 3]);
          *(float4*)&mb[strip * 4096 + db * 1024 + q4 * 256 + lane * 4] = v;
        }
      if (lane < 32) { ml[strip * 64 + lane] = m_run; ml[strip * 64 + 32 + lane] = l_run; }
    }
    __syncthreads();
    if (half == 0) {
      const float mp = ml[strip * 64 + l31];
      const float lp = ml[strip * 64 + 32 + l31];
      const float M  = fmaxf(m_run, mp);
      const float sA = __expf(m_run - M);
      const float sB = __expf(mp - M);
      const float inv = 1.0f / (l_run * sA + lp * sB);
      const float fAl = sA * inv, fBl = sB * inv;
      float fA[16], fB[16];
#pragma unroll
      for (int r = 0; r < 16; ++r) {
        const int cr_ = (r & 3) + 8 * (r >> 2) + 4 * hi;
        fA[r] = __shfl(fAl, cr_);
        fB[r] = __shfl(fBl, cr_);
      }
#pragma unroll
      for (int db = 0; db < 4; ++db)
#pragma unroll
        for (int q4 = 0; q4 < 4; ++q4) {
          float4 pv = *(const float4*)&mb[strip * 4096 + db * 1024 + q4 * 256 + lane * 4];
#pragma unroll
          for (int jj = 0; jj < 4; ++jj) {
            const int r = q4 * 4 + jj;
            const int cr_ = (r & 3) + 8 * (r >> 2) + 4 * hi;
            const float pvj = (jj == 0) ? pv.x : (jj == 1) ? pv.y : (jj == 2) ? pv.z : pv.w;
            out[((size_t)(tok0 + q0 + cr_) * Hz + h) * 128 + db * 32 + l31] =
                acc[db][r] * fA[r] + pvj * fB[r];
          }
        }
    }
    __syncthreads();   // before next pass re-stages LDS
  }
}

// ---------------------------------------------------------------- launch
extern "C" void kernel_launch(void* const* d_in, const int* in_sizes, int n_in,
                              void* d_out, int out_size, void* d_ws, size_t ws_size,
                              hipStream_t stream) {
  const float* q    = (const float*)d_in[0];
  const float* ckv  = (const float*)d_in[1];
  const float* rope = (const float*)d_in[2];
  const float* wup  = (const float*)d_in[3];
  float* out = (float*)d_out;

  u16* ckvb  = (u16*)d_ws;
  u16* wupb  = ckvb + (size_t)4096 * RANKz;
  u16* kvb   = wupb + (size_t)4096 * RANKz;
  u16* ropeb = kvb + (size_t)4096 * 4096;

  const int nvec = 4096 * RANKz / 4;       // 524288 float4 per matrix
  const int nrope = 4096 * 64 / 4;         // 65536 float4
  cvt_bf16_kernel<<<(2 * nvec + nrope) / 256, 256, 0, stream>>>(ckv, ckvb, wup, wupb, rope, ropeb, nvec, nvec);

  dim3 gg(32, 32);
  gemm_kv_bf16<<<gg, 256, 0, stream>>>(ckvb, wupb, kvb);

  mla_attn_mfma<<<256, 512, 0, stream>>>(q, kvb, ropeb, out);
}

// Round 12
// 102.854 us; speedup vs baseline: 1.4358x; 1.0704x over previous
//
#include <hip/hip_runtime.h>
#include <stdint.h>

// MLA attention, MI355X round 12.
// Stage 1: kv = compressed_kv @ w_up^T  (bf16 MFMA, m97-style 128x128 tile)
// Stage 2: causal flash attention, 8-wave swapped-QK^T 32x32x16 (r8 math)
//   + r12: depth-2 async pipeline. KV-64 tiles, TRIPLE-buffered LDS
//   (Kn 3x16K @0, Kr 3x8K @48K, Vt 3x16K @72K = 120K), 2 V-reg sets.
//   Round t: issue K/V(t+2), compute t, writeVt(t+1) [round-old regs],
//   then s_waitcnt vmcnt(5) + RAW s_barrier (counted, never drain in steady
//   state) — removes the per-round vmcnt(0) drain __syncthreads imposes,
//   which the r2..r11 invariant (~3.5us per KV-64 unit across 4 structures)
//   identified as the exposed-latency serializer.
//   Balance: 256 blocks, block = pass pair (7-pr, pr) = 18 rounds; XCD-chunk bh.

#define Hz 16
#define Sz 1024
#define RANKz 512
#define SCALEf 0.07216878364870323f
#define CRr(r) ((((r) & 3)) + 8 * ((r) >> 2) + 4 * hi)

typedef unsigned short u16;
typedef __attribute__((ext_vector_type(8))) short bf16x8;
typedef __attribute__((ext_vector_type(4))) float f32x4;
typedef __attribute__((ext_vector_type(16))) float f32x16;

__device__ __forceinline__ u16 f2b(float f) {
  union { float f; uint32_t u; } x; x.f = f;
  return (u16)((x.u + 0x7fffu + ((x.u >> 16) & 1u)) >> 16);
}
__device__ __forceinline__ uint32_t cvtpk(float lo, float hi_) {
  uint32_t r;
  asm("v_cvt_pk_bf16_f32 %0, %1, %2" : "=v"(r) : "v"(lo), "v"(hi_));
  return r;
}

// ---------------------------------------------------------------- cvt fp32->bf16
__global__ void cvt_bf16_kernel(const float* __restrict__ a, u16* __restrict__ ao,
                                const float* __restrict__ b, u16* __restrict__ bo,
                                const float* __restrict__ c, u16* __restrict__ co,
                                int na, int nb) {
  int idx = blockIdx.x * blockDim.x + threadIdx.x;
  const float* s; u16* d; int i;
  if (idx < na)            { s = a; d = ao; i = idx; }
  else if (idx < na + nb)  { s = b; d = bo; i = idx - na; }
  else                     { s = c; d = co; i = idx - na - nb; }
  float4 v = ((const float4*)s)[i];
  ushort4 o = make_ushort4(f2b(v.x), f2b(v.y), f2b(v.z), f2b(v.w));
  ((ushort4*)d)[i] = o;
}

// ---------------------------------------------------------------- stage 1 GEMM
__global__ __launch_bounds__(256)
void gemm_kv_bf16(const u16* __restrict__ A,
                  const u16* __restrict__ Bm,
                  u16* __restrict__ C) {
  __shared__ u16 As[128 * 32];
  __shared__ u16 Bs[128 * 32];
  const int tid = threadIdx.x;
  const int w = tid >> 6, lane = tid & 63;
  const int wr = w >> 1, wc = w & 1;
  const int row0 = blockIdx.x * 128, col0 = blockIdx.y * 128;
  f32x4 acc[4][4];
#pragma unroll
  for (int m = 0; m < 4; ++m)
#pragma unroll
    for (int n = 0; n < 4; ++n) acc[m][n] = (f32x4){0.f, 0.f, 0.f, 0.f};

  const int rstage = (lane >> 2);
  const int cstage = (lane & 3) * 8;

  for (int kt = 0; kt < RANKz / 32; ++kt) {
    const int k0 = kt * 32;
#pragma unroll
    for (int i = 0; i < 2; ++i) {
      const int chunk = i * 4 + w;
      const int r = chunk * 16 + rstage;
      const u16* ga = A  + (size_t)(row0 + r) * RANKz + k0 + cstage;
      const u16* gb = Bm + (size_t)(col0 + r) * RANKz + k0 + cstage;
      __builtin_amdgcn_global_load_lds((const __attribute__((address_space(1))) void*)ga,
                                       (__attribute__((address_space(3))) void*)&As[chunk * 512], 16, 0, 0);
      __builtin_amdgcn_global_load_lds((const __attribute__((address_space(1))) void*)gb,
                                       (__attribute__((address_space(3))) void*)&Bs[chunk * 512], 16, 0, 0);
    }
    __syncthreads();
    const int klo = (lane >> 4) * 8;
    bf16x8 af[4], bfr[4];
#pragma unroll
    for (int m = 0; m < 4; ++m)
      af[m] = *(const bf16x8*)&As[(wr * 64 + m * 16 + (lane & 15)) * 32 + klo];
#pragma unroll
    for (int n = 0; n < 4; ++n)
      bfr[n] = *(const bf16x8*)&Bs[(wc * 64 + n * 16 + (lane & 15)) * 32 + klo];
#pragma unroll
    for (int m = 0; m < 4; ++m)
#pragma unroll
      for (int n = 0; n < 4; ++n)
        acc[m][n] = __builtin_amdgcn_mfma_f32_16x16x32_bf16(af[m], bfr[n], acc[m][n], 0, 0, 0);
    __syncthreads();
  }
  const int cb = col0 + wc * 64 + (lane & 15);
  const int rb = row0 + wr * 64 + (lane >> 4) * 4;
#pragma unroll
  for (int m = 0; m < 4; ++m)
#pragma unroll
    for (int n = 0; n < 4; ++n)
#pragma unroll
      for (int j = 0; j < 4; ++j)
        C[(size_t)(rb + m * 16 + j) * 4096 + (cb + n * 16)] = f2b(acc[m][n][j]);
}

// ---------------------------------------------------------------- stage 2: attention
// LDS (123904): Kn[b]@b*16K (3x16K), Kr[b]@49152+b*8K (3x8K), Vt[b]@73728+b*16K
// (3x16K), ml@122880. Merge overlay mb@0 (64K, over Kn0-2+Kr0-1, all consumed).
__global__ __launch_bounds__(512, 1)
void mla_attn_mfma(const float* __restrict__ q,
                   const u16* __restrict__ kvb,     // [T][16][256] bf16
                   const u16* __restrict__ ropeb,   // [T][64] bf16
                   float* __restrict__ out) {       // [T][16][128] fp32
  __shared__ __align__(16) unsigned char LB[123904];

  const int tid = threadIdx.x;
  const int w = tid >> 6, lane = tid & 63;
  const int l31 = lane & 31, hi = lane >> 5;
  const int half = w >> 2, strip = w & 3;

  const int bid = blockIdx.x;
  const int job = (bid & 7) * 32 + (bid >> 3);   // same-bh jobs -> same XCD
  const int bh = job >> 2, pr = job & 3;
  const int bat = bh >> 4, h = bh & 15;
  const int tok0 = bat * Sz;

  const int vkp = tid & 31, vdc = tid >> 5;      // V stage: k-pair 0..31, d-chunk8 0..15

  auto stageK = [&](int tokt, int buf) {
#pragma unroll
    for (int i = 0; i < 2; ++i) {                // Kn: 16 chunks of 1KB
      const int c = w * 2 + i;
      const int row = c * 4 + (lane >> 4);
      const int sc = (lane & 15) ^ (row & 7);
      const u16* src = kvb + ((size_t)(tokt + row) * Hz + h) * 256 + sc * 8;
      __builtin_amdgcn_global_load_lds((const __attribute__((address_space(1))) void*)src,
                                       (__attribute__((address_space(3))) void*)(LB + buf * 16384 + c * 1024), 16, 0, 0);
    }
    {                                            // Kr: 8 chunks of 1KB
      const int c = w;
      const int row = c * 8 + (lane >> 3);
      const int sc = (lane & 7) ^ (row & 7);
      const u16* src = ropeb + (size_t)(tokt + row) * 64 + sc * 8;
      __builtin_amdgcn_global_load_lds((const __attribute__((address_space(1))) void*)src,
                                       (__attribute__((address_space(3))) void*)(LB + 49152 + buf * 8192 + c * 1024), 16, 0, 0);
    }
  };
  auto loadV = [&](int tokt, uint4& va, uint4& vb) {
    const u16* vp = kvb + ((size_t)(tokt + vkp * 2) * Hz + h) * 256 + 128 + vdc * 8;
    va = *(const uint4*)vp;                      // token 2*vkp
    vb = *(const uint4*)(vp + Hz * 256);         // token 2*vkp+1
  };
  auto writeVt = [&](int buf, uint4 va, uint4 vb) {
    union { uint4 v; u16 u[8]; } A_, B_;
    A_.v = va; B_.v = vb;
    uint32_t* vt = (uint32_t*)(LB + 73728 + buf * 16384);
#pragma unroll
    for (int i = 0; i < 8; ++i) {
      const int d = vdc * 8 + i;
      vt[d * 32 + 4 * ((vkp >> 2) ^ (d & 7)) + (vkp & 3)] =
          (uint32_t)A_.u[i] | ((uint32_t)B_.u[i] << 16);
    }
  };

#pragma unroll 1
  for (int pass = 0; pass < 2; ++pass) {
    const int qt = pass ? pr : (7 - pr);
    const int nt = 2 * qt + 2;                   // KV-64 rounds (always even, >= 2)
    const int q0 = qt * 128 + strip * 32;

    // ---- Q fragments (B-operand), prescaled by SCALE
    bf16x8 qf[12];
    {
      const float* qp = q + ((size_t)(tok0 + q0 + l31) * Hz + h) * 192 + hi * 8;
#pragma unroll
      for (int ds = 0; ds < 12; ++ds) {
        float4 a = *(const float4*)(qp + ds * 16);
        float4 b = *(const float4*)(qp + ds * 16 + 4);
        union { bf16x8 v; u16 u[8]; } t;
        t.u[0] = f2b(a.x * SCALEf); t.u[1] = f2b(a.y * SCALEf);
        t.u[2] = f2b(a.z * SCALEf); t.u[3] = f2b(a.w * SCALEf);
        t.u[4] = f2b(b.x * SCALEf); t.u[5] = f2b(b.y * SCALEf);
        t.u[6] = f2b(b.z * SCALEf); t.u[7] = f2b(b.w * SCALEf);
        qf[ds] = t.v;
      }
    }

    f32x16 acc[4];
#pragma unroll
    for (int db = 0; db < 4; ++db)
#pragma unroll
      for (int r = 0; r < 16; ++r) acc[db][r] = 0.f;
    float m_run = -1e30f, l_run = 0.f;

    uint4 vaA, vbA, vaB, vbB;                    // two V prefetch sets

    // ---- prologue: stage tiles 0,1 (depth 2)
    stageK(tok0, 0);            loadV(tok0, vaA, vbA);
    stageK(tok0 + 64, 1);       loadV(tok0 + 64, vaB, vbB);
    writeVt(0, vaA, vbA);                        // compiler waits V(0) only
    asm volatile("s_waitcnt vmcnt(5) lgkmcnt(0)" ::: "memory");
    __builtin_amdgcn_s_barrier();                // Kn/Kr(0) staged, Vt(0) visible
    __builtin_amdgcn_sched_barrier(0);

    auto round = [&](int t, uint4& iva, uint4& ivb, uint4& wva, uint4& wvb) {
      const bool issue = (t + 2 < nt);
      if (issue) {
        stageK(tok0 + (t + 2) * 64, (t + 2) % 3);
        loadV(tok0 + (t + 2) * 64, iva, ivb);
      }

      const int kb = t * 64 + half * 32;
      if (kb <= q0 + 31) {                       // wave-active
        const int bufC = t % 3;
        const u16* KnC = (const u16*)(LB + bufC * 16384);
        const u16* KrC = (const u16*)(LB + 49152 + bufC * 8192);
        const u16* VtC = (const u16*)(LB + 73728 + bufC * 16384);
        const int row_a = half * 32 + l31;
        const int swz = row_a & 7;

        f32x16 s0;
#pragma unroll
        for (int r = 0; r < 16; ++r) s0[r] = 0.f;
        __builtin_amdgcn_s_setprio(1);
#pragma unroll
        for (int ds = 0; ds < 8; ++ds) {
          bf16x8 kf = *(const bf16x8*)&KnC[row_a * 128 + 8 * ((2 * ds + hi) ^ swz)];
          s0 = __builtin_amdgcn_mfma_f32_32x32x16_bf16(kf, qf[ds], s0, 0, 0, 0);
        }
#pragma unroll
        for (int ds = 0; ds < 4; ++ds) {
          bf16x8 kf = *(const bf16x8*)&KrC[row_a * 64 + 8 * ((2 * ds + hi) ^ swz)];
          s0 = __builtin_amdgcn_mfma_f32_32x32x16_bf16(kf, qf[8 + ds], s0, 0, 0, 0);
        }
        __builtin_amdgcn_s_setprio(0);

        // ---- causal mask (edge sub-tiles only)
        if (kb + 31 > q0) {
#pragma unroll
          for (int r = 0; r < 16; ++r)
            if (kb + CRr(r) > q0 + l31) s0[r] = -1e30f;
        }

        // ---- online softmax (lane owns q-col l31), tree reduce, defer-max
        float ma0 = fmaxf(s0[0], s0[1]),   ma1 = fmaxf(s0[2], s0[3]);
        float ma2 = fmaxf(s0[4], s0[5]),   ma3 = fmaxf(s0[6], s0[7]);
        float ma4 = fmaxf(s0[8], s0[9]),   ma5 = fmaxf(s0[10], s0[11]);
        float ma6 = fmaxf(s0[12], s0[13]), ma7 = fmaxf(s0[14], s0[15]);
        float mx = fmaxf(fmaxf(fmaxf(ma0, ma1), fmaxf(ma2, ma3)),
                         fmaxf(fmaxf(ma4, ma5), fmaxf(ma6, ma7)));
        mx = fmaxf(mx, __shfl_xor(mx, 32));
        if (__any(mx > m_run + 8.f)) {
          const float nm = fmaxf(m_run, mx);
          const float cr = __expf(m_run - nm);
          m_run = nm; l_run *= cr;
#pragma unroll
          for (int r = 0; r < 16; ++r) {
            const float crg = __shfl(cr, CRr(r));
#pragma unroll
            for (int db = 0; db < 4; ++db) acc[db][r] *= crg;
          }
        }
#pragma unroll
        for (int r = 0; r < 16; ++r) s0[r] = __expf(s0[r] - m_run);
        float e0 = s0[0] + s0[1],   e1 = s0[2] + s0[3];
        float e2 = s0[4] + s0[5],   e3 = s0[6] + s0[7];
        float e4 = s0[8] + s0[9],   e5 = s0[10] + s0[11];
        float e6 = s0[12] + s0[13], e7 = s0[14] + s0[15];
        float ts = ((e0 + e1) + (e2 + e3)) + ((e4 + e5) + (e6 + e7));
        ts += __shfl_xor(ts, 32);
        l_run += ts;

        // ---- P -> A-frags: cvt_pk + xor-32 word swap
        bf16x8 pf[2];
#pragma unroll
        for (int ks = 0; ks < 2; ++ks) {
          const int o = ks * 8;
          const uint32_t w0 = cvtpk(s0[o + 0], s0[o + 1]);
          const uint32_t w1 = cvtpk(s0[o + 4], s0[o + 5]);
          const uint32_t w2 = cvtpk(s0[o + 2], s0[o + 3]);
          const uint32_t w3 = cvtpk(s0[o + 6], s0[o + 7]);
          const uint32_t t0 = __shfl_xor(w0, 32), t1 = __shfl_xor(w1, 32);
          const uint32_t t2 = __shfl_xor(w2, 32), t3 = __shfl_xor(w3, 32);
          union { bf16x8 v; uint32_t u[4]; } P;
          P.u[0] = hi ? t1 : w0;
          P.u[1] = hi ? t3 : w2;
          P.u[2] = hi ? w1 : t0;
          P.u[3] = hi ? w3 : t2;
          pf[ks] = P.v;
        }

        // ---- PV: O[32q x 128d] += P[32q x 32k] * V[32k x 128d]
        __builtin_amdgcn_s_setprio(1);
#pragma unroll
        for (int ks = 0; ks < 2; ++ks)
#pragma unroll
          for (int db = 0; db < 4; ++db) {
            const int d = db * 32 + l31;
            bf16x8 vf = *(const bf16x8*)&VtC[d * 64 + 8 * ((half * 4 + 2 * ks + hi) ^ (d & 7))];
            acc[db] = __builtin_amdgcn_mfma_f32_32x32x16_bf16(pf[ks], vf, acc[db], 0, 0, 0);
          }
        __builtin_amdgcn_s_setprio(0);
      }

      if (t + 1 < nt) writeVt((t + 1) % 3, wva, wvb);   // round-old regs: no wait

      if (issue) { asm volatile("s_waitcnt vmcnt(5) lgkmcnt(0)" ::: "memory"); }
      else       { asm volatile("s_waitcnt vmcnt(0) lgkmcnt(0)" ::: "memory"); }
      __builtin_amdgcn_s_barrier();              // t+1 fully staged; t consumed
      __builtin_amdgcn_sched_barrier(0);
    };

#pragma unroll 1
    for (int t = 0; t < nt; t += 2) {
      round(t,     vaA, vbA, vaB, vbB);          // issues V(t+2)->A, writes Vt(t+1) from B
      round(t + 1, vaB, vbB, vaA, vbA);          // issues V(t+3)->B, writes Vt(t+2) from A
    }

    // ---- merge the two k-halves (fp32 partials through LDS), write out
    float* mb = (float*)LB;                      // 64K overlay (Kn + Kr b0/b1, consumed)
    float* ml = (float*)(LB + 122880);
    if (half == 1) {
#pragma unroll
      for (int db = 0; db < 4; ++db)
#pragma unroll
        for (int g = 0; g < 4; ++g) {
          float4 v = make_float4(acc[db][g * 4 + 0], acc[db][g * 4 + 1],
                                 acc[db][g * 4 + 2], acc[db][g * 4 + 3]);
          *(float4*)&mb[strip * 4096 + db * 1024 + g * 256 + lane * 4] = v;
        }
      if (lane < 32) { ml[strip * 64 + lane] = m_run; ml[strip * 64 + 32 + lane] = l_run; }
    }
    __syncthreads();
    if (half == 0) {
      const float mp = ml[strip * 64 + l31];
      const float lp = ml[strip * 64 + 32 + l31];
      const float M  = fmaxf(m_run, mp);
      const float sA = __expf(m_run - M);
      const float sB = __expf(mp - M);
      const float inv = 1.0f / (l_run * sA + lp * sB);
      const float fAl = sA * inv, fBl = sB * inv;
      float fA[16], fB[16];
#pragma unroll
      for (int r = 0; r < 16; ++r) { fA[r] = __shfl(fAl, CRr(r)); fB[r] = __shfl(fBl, CRr(r)); }
#pragma unroll
      for (int db = 0; db < 4; ++db)
#pragma unroll
        for (int g = 0; g < 4; ++g) {
          float4 pv = *(const float4*)&mb[strip * 4096 + db * 1024 + g * 256 + lane * 4];
#pragma unroll
          for (int jj = 0; jj < 4; ++jj) {
            const int r = g * 4 + jj;
            const float pvj = (jj == 0) ? pv.x : (jj == 1) ? pv.y : (jj == 2) ? pv.z : pv.w;
            out[((size_t)(tok0 + q0 + CRr(r)) * Hz + h) * 128 + db * 32 + l31] =
                acc[db][r] * fA[r] + pvj * fB[r];
          }
        }
    }
    __syncthreads();                             // before next pass re-stages LDS
  }
}

// ---------------------------------------------------------------- launch
extern "C" void kernel_launch(void* const* d_in, const int* in_sizes, int n_in,
                              void* d_out, int out_size, void* d_ws, size_t ws_size,
                              hipStream_t stream) {
  const float* q    = (const float*)d_in[0];
  const float* ckv  = (const float*)d_in[1];
  const float* rope = (const float*)d_in[2];
  const float* wup  = (const float*)d_in[3];
  float* out = (float*)d_out;

  u16* ckvb  = (u16*)d_ws;
  u16* wupb  = ckvb + (size_t)4096 * RANKz;
  u16* kvb   = wupb + (size_t)4096 * RANKz;
  u16* ropeb = kvb + (size_t)4096 * 4096;

  const int nvec = 4096 * RANKz / 4;       // 524288 float4 per matrix
  const int nrope = 4096 * 64 / 4;         // 65536 float4
  cvt_bf16_kernel<<<(2 * nvec + nrope) / 256, 256, 0, stream>>>(ckv, ckvb, wup, wupb, rope, ropeb, nvec, nvec);

  dim3 gg(32, 32);
  gemm_kv_bf16<<<gg, 256, 0, stream>>>(ckvb, wupb, kvb);

  mla_attn_mfma<<<256, 512, 0, stream>>>(q, kvb, ropeb, out);
}

// Round 13
// 95.719 us; speedup vs baseline: 1.5428x; 1.0745x over previous
//
#include <hip/hip_runtime.h>
#include <stdint.h>

// MLA attention, MI355X round 13 = round 5 (best measured: attn 65us, total 90us)
// restored, plus two zero-risk tweaks:
//  (1) V/rope global loads issued BEFORE the K global_load_lds batch each tile:
//      writeVt's register wait becomes vmcnt(6) instead of a full drain, so the
//      Vt ds_write overlaps the K-gll tail (~200-400cy/tile earlier barrier B).
//  (2) GEMM XCD swizzle (T1): 1D grid 1024, each XCD owns 4 B-column panels.
// Structure (verified r5): 8-wave swapped-QK^T 32x32x16, wave=(k-half, q-strip),
// q-tile 128, KV tile 128, Kn/Kr gll XOR-swizzled dbuf, Vt single-buffer packed
// transpose (2 barriers/tile), per-k-half online softmax merged at pass end,
// block = q-tile pair (7-pr, pr) = 9 tiles, XCD-chunked bh.

#define Hz 16
#define Sz 1024
#define RANKz 512
#define SCALEf 0.07216878364870323f

typedef unsigned short u16;
typedef __attribute__((ext_vector_type(8))) short bf16x8;
typedef __attribute__((ext_vector_type(4))) float f32x4;
typedef __attribute__((ext_vector_type(16))) float f32x16;

__device__ __forceinline__ u16 f2b(float f) {
  union { float f; uint32_t u; } x; x.f = f;
  return (u16)((x.u + 0x7fffu + ((x.u >> 16) & 1u)) >> 16);
}
__device__ __forceinline__ uint32_t cvtpk(float lo, float hi_) {
  uint32_t r;
  asm("v_cvt_pk_bf16_f32 %0, %1, %2" : "=v"(r) : "v"(lo), "v"(hi_));
  return r;
}

// ---------------------------------------------------------------- cvt fp32->bf16
__global__ void cvt_bf16_kernel(const float* __restrict__ a, u16* __restrict__ ao,
                                const float* __restrict__ b, u16* __restrict__ bo,
                                const float* __restrict__ c, u16* __restrict__ co,
                                int na, int nb) {
  int idx = blockIdx.x * blockDim.x + threadIdx.x;
  const float* s; u16* d; int i;
  if (idx < na)            { s = a; d = ao; i = idx; }
  else if (idx < na + nb)  { s = b; d = bo; i = idx - na; }
  else                     { s = c; d = co; i = idx - na - nb; }
  float4 v = ((const float4*)s)[i];
  ushort4 o = make_ushort4(f2b(v.x), f2b(v.y), f2b(v.z), f2b(v.w));
  ((ushort4*)d)[i] = o;
}

// ---------------------------------------------------------------- stage 1 GEMM
// 1D grid 1024; XCD swizzle: bids [x*128,(x+1)*128) -> col panels [x*4,x*4+4)
__global__ __launch_bounds__(256)
void gemm_kv_bf16(const u16* __restrict__ A,
                  const u16* __restrict__ Bm,
                  u16* __restrict__ C) {
  __shared__ u16 As[128 * 32];
  __shared__ u16 Bs[128 * 32];
  const int tid = threadIdx.x;
  const int w = tid >> 6, lane = tid & 63;
  const int wr = w >> 1, wc = w & 1;
  const int swz = (blockIdx.x & 7) * 128 + (blockIdx.x >> 3);  // bijective (1024%8==0)
  const int row0 = (swz & 31) * 128, col0 = (swz >> 5) * 128;
  f32x4 acc[4][4];
#pragma unroll
  for (int m = 0; m < 4; ++m)
#pragma unroll
    for (int n = 0; n < 4; ++n) acc[m][n] = (f32x4){0.f, 0.f, 0.f, 0.f};

  const int rstage = (lane >> 2);
  const int cstage = (lane & 3) * 8;

  for (int kt = 0; kt < RANKz / 32; ++kt) {
    const int k0 = kt * 32;
#pragma unroll
    for (int i = 0; i < 2; ++i) {
      const int chunk = i * 4 + w;
      const int r = chunk * 16 + rstage;
      const u16* ga = A  + (size_t)(row0 + r) * RANKz + k0 + cstage;
      const u16* gb = Bm + (size_t)(col0 + r) * RANKz + k0 + cstage;
      __builtin_amdgcn_global_load_lds((const __attribute__((address_space(1))) void*)ga,
                                       (__attribute__((address_space(3))) void*)&As[chunk * 512], 16, 0, 0);
      __builtin_amdgcn_global_load_lds((const __attribute__((address_space(1))) void*)gb,
                                       (__attribute__((address_space(3))) void*)&Bs[chunk * 512], 16, 0, 0);
    }
    __syncthreads();
    const int klo = (lane >> 4) * 8;
    bf16x8 af[4], bfr[4];
#pragma unroll
    for (int m = 0; m < 4; ++m)
      af[m] = *(const bf16x8*)&As[(wr * 64 + m * 16 + (lane & 15)) * 32 + klo];
#pragma unroll
    for (int n = 0; n < 4; ++n)
      bfr[n] = *(const bf16x8*)&Bs[(wc * 64 + n * 16 + (lane & 15)) * 32 + klo];
#pragma unroll
    for (int m = 0; m < 4; ++m)
#pragma unroll
      for (int n = 0; n < 4; ++n)
        acc[m][n] = __builtin_amdgcn_mfma_f32_16x16x32_bf16(af[m], bfr[n], acc[m][n], 0, 0, 0);
    __syncthreads();
  }
  const int cb = col0 + wc * 64 + (lane & 15);
  const int rb = row0 + wr * 64 + (lane >> 4) * 4;
#pragma unroll
  for (int m = 0; m < 4; ++m)
#pragma unroll
    for (int n = 0; n < 4; ++n)
#pragma unroll
      for (int j = 0; j < 4; ++j)
        C[(size_t)(rb + m * 16 + j) * 4096 + (cb + n * 16)] = f2b(acc[m][n][j]);
}

// ---------------------------------------------------------------- stage 2: attention
// grid 256 x 1, block 512 = 8 waves. wave = (half = w>>2, strip = w&3).
// LDS map: Kn dbuf @0 (2x32K) Kr dbuf @64K (2x16K) Vt @96K (32K). 128K total.
__global__ __launch_bounds__(512, 2)
void mla_attn_mfma(const float* __restrict__ q,
                   const u16* __restrict__ kvb,     // [T][16][256] bf16
                   const u16* __restrict__ ropeb,   // [T][64] bf16
                   float* __restrict__ out) {       // [T][16][128] fp32
  __shared__ __align__(16) unsigned char LB[131072];

  const int tid = threadIdx.x;
  const int w = tid >> 6, lane = tid & 63;
  const int l31 = lane & 31, hi = lane >> 5;
  const int half = w >> 2, strip = w & 3;

  const int bid = blockIdx.x;
  const int job = (bid & 7) * 32 + (bid >> 3);   // same-bh jobs -> same XCD
  const int bh = job >> 2, pr = job & 3;
  const int bat = bh >> 4, h = bh & 15;
  const int tok0 = bat * Sz;

  const int vkp = tid & 63, vdc = (tid >> 6) & 7;  // V stage: k-pair, d-chunk16

#pragma unroll 1
  for (int pass = 0; pass < 2; ++pass) {
    const int qt = pass ? pr : (7 - pr);
    const int ntiles = qt + 1;
    const int q0 = qt * 128 + strip * 32;         // wave's q-strip base (in-batch)

    // ---- Q fragments (B-operand), prescaled by SCALE
    bf16x8 qf[12];
    {
      const float* qp = q + ((size_t)(tok0 + q0 + l31) * Hz + h) * 192 + hi * 8;
#pragma unroll
      for (int ds = 0; ds < 12; ++ds) {
        float4 a = *(const float4*)(qp + ds * 16);
        float4 b = *(const float4*)(qp + ds * 16 + 4);
        union { bf16x8 v; u16 u[8]; } t;
        t.u[0] = f2b(a.x * SCALEf); t.u[1] = f2b(a.y * SCALEf);
        t.u[2] = f2b(a.z * SCALEf); t.u[3] = f2b(a.w * SCALEf);
        t.u[4] = f2b(b.x * SCALEf); t.u[5] = f2b(b.y * SCALEf);
        t.u[6] = f2b(b.z * SCALEf); t.u[7] = f2b(b.w * SCALEf);
        qf[ds] = t.v;
      }
    }

    f32x16 acc[4];
#pragma unroll
    for (int db = 0; db < 4; ++db)
#pragma unroll
      for (int r = 0; r < 16; ++r) acc[db][r] = 0.f;
    float m_run = -1e30f, l_run = 0.f;

    uint4 va0, va1, vb0, vb1;   // V prefetch regs (16 VGPR)

    // ---- prologue: stage tile 0 (V first: writeVt waits vmcnt(6), not drain)
    {
      const int tokt = tok0;
      const u16* vp = kvb + ((size_t)(tokt + vkp * 2) * Hz + h) * 256 + 128 + vdc * 16;
      va0 = *(const uint4*)(vp);
      va1 = *(const uint4*)(vp + 8);
      vb0 = *(const uint4*)(vp + Hz * 256);
      vb1 = *(const uint4*)(vp + Hz * 256 + 8);
#pragma unroll
      for (int i = 0; i < 4; ++i) {              // Kn: 32 chunks of 1KB
        const int c = w * 4 + i;
        const int row = c * 4 + (lane >> 4);
        const int sc = (lane & 15) ^ (row & 7);
        const u16* src = kvb + ((size_t)(tokt + row) * Hz + h) * 256 + sc * 8;
        __builtin_amdgcn_global_load_lds((const __attribute__((address_space(1))) void*)src,
                                         (__attribute__((address_space(3))) void*)(LB + c * 1024), 16, 0, 0);
      }
#pragma unroll
      for (int i = 0; i < 2; ++i) {              // Kr: 16 chunks of 1KB
        const int c = w * 2 + i;
        const int row = c * 8 + (lane >> 3);
        const int sc = (lane & 7) ^ (row & 7);
        const u16* src = ropeb + (size_t)(tokt + row) * 64 + sc * 8;
        __builtin_amdgcn_global_load_lds((const __attribute__((address_space(1))) void*)src,
                                         (__attribute__((address_space(3))) void*)(LB + 65536 + c * 1024), 16, 0, 0);
      }
    }
    __syncthreads();
    { // write Vt(0): pack k-pairs, swizzle chunk ^= (d&7)
      union { uint4 v; u16 u[8]; } A0, A1, B0, B1;
      A0.v = va0; A1.v = va1; B0.v = vb0; B1.v = vb1;
      char* vt = (char*)(LB + 98304);
      const int inb = (4 * vkp) & 15, cc = vkp >> 2;
#pragma unroll
      for (int i = 0; i < 8; ++i) {
        { const int d = vdc * 16 + i;
          uint32_t wv = (uint32_t)A0.u[i] | ((uint32_t)B0.u[i] << 16);
          *(uint32_t*)(vt + d * 256 + 16 * (cc ^ (d & 7)) + inb) = wv; }
        { const int d = vdc * 16 + 8 + i;
          uint32_t wv = (uint32_t)A1.u[i] | ((uint32_t)B1.u[i] << 16);
          *(uint32_t*)(vt + d * 256 + 16 * (cc ^ (d & 7)) + inb) = wv; }
      }
    }
    __syncthreads();

#pragma unroll 1
    for (int t = 0; t < ntiles; ++t) {
      const int cur = t & 1;
      const bool havenext = (t + 1 < ntiles);
      if (havenext) {   // V(t+1) regs first, then gll K(t+1) into buf cur^1
        const int tokt = tok0 + (t + 1) * 128;
        const u16* vp = kvb + ((size_t)(tokt + vkp * 2) * Hz + h) * 256 + 128 + vdc * 16;
        va0 = *(const uint4*)(vp);
        va1 = *(const uint4*)(vp + 8);
        vb0 = *(const uint4*)(vp + Hz * 256);
        vb1 = *(const uint4*)(vp + Hz * 256 + 8);
#pragma unroll
        for (int i = 0; i < 4; ++i) {
          const int c = w * 4 + i;
          const int row = c * 4 + (lane >> 4);
          const int sc = (lane & 15) ^ (row & 7);
          const u16* src = kvb + ((size_t)(tokt + row) * Hz + h) * 256 + sc * 8;
          __builtin_amdgcn_global_load_lds((const __attribute__((address_space(1))) void*)src,
                                           (__attribute__((address_space(3))) void*)(LB + (cur ^ 1) * 32768 + c * 1024), 16, 0, 0);
        }
#pragma unroll
        for (int i = 0; i < 2; ++i) {
          const int c = w * 2 + i;
          const int row = c * 8 + (lane >> 3);
          const int sc = (lane & 7) ^ (row & 7);
          const u16* src = ropeb + (size_t)(tokt + row) * 64 + sc * 8;
          __builtin_amdgcn_global_load_lds((const __attribute__((address_space(1))) void*)src,
                                           (__attribute__((address_space(3))) void*)(LB + 65536 + (cur ^ 1) * 16384 + c * 1024), 16, 0, 0);
        }
      }

      const bool active = (t * 128 + half * 64) <= (q0 + 31);
      if (active) {
        const u16* KnC = (const u16*)(LB + cur * 32768);
        const u16* KrC = (const u16*)(LB + 65536 + cur * 16384);
        // ---- swapped QK^T: S^T[64k x 32q], accumulate over d
        f32x16 s0, s1;
#pragma unroll
        for (int r = 0; r < 16; ++r) { s0[r] = 0.f; s1[r] = 0.f; }
        const int row_a = half * 64 + l31;        // kh=0 k-row
        const int row_b = row_a + 32;             // kh=1 k-row
#pragma unroll
        for (int ds = 0; ds < 8; ++ds) {
          bf16x8 k0v = *(const bf16x8*)&KnC[row_a * 128 + 8 * ((2 * ds + hi) ^ (row_a & 7))];
          bf16x8 k1v = *(const bf16x8*)&KnC[row_b * 128 + 8 * ((2 * ds + hi) ^ (row_b & 7))];
          s0 = __builtin_amdgcn_mfma_f32_32x32x16_bf16(k0v, qf[ds], s0, 0, 0, 0);
          s1 = __builtin_amdgcn_mfma_f32_32x32x16_bf16(k1v, qf[ds], s1, 0, 0, 0);
        }
#pragma unroll
        for (int ds = 8; ds < 12; ++ds) {
          bf16x8 k0v = *(const bf16x8*)&KrC[row_a * 64 + 8 * ((2 * (ds - 8) + hi) ^ (row_a & 7))];
          bf16x8 k1v = *(const bf16x8*)&KrC[row_b * 64 + 8 * ((2 * (ds - 8) + hi) ^ (row_b & 7))];
          s0 = __builtin_amdgcn_mfma_f32_32x32x16_bf16(k0v, qf[ds], s0, 0, 0, 0);
          s1 = __builtin_amdgcn_mfma_f32_32x32x16_bf16(k1v, qf[ds], s1, 0, 0, 0);
        }

        // ---- causal mask (diagonal tile only)
        if (t == qt) {
          const int qg = q0 + l31;
          const int kb0 = t * 128 + half * 64;
#pragma unroll
          for (int r = 0; r < 16; ++r) {
            const int cr_ = (r & 3) + 8 * (r >> 2) + 4 * hi;
            if (kb0 + cr_ > qg)      s0[r] = -1e30f;
            if (kb0 + 32 + cr_ > qg) s1[r] = -1e30f;
          }
        }

        // ---- in-register online softmax (lane owns q-column l31)
        float mx = -1e30f;
#pragma unroll
        for (int r = 0; r < 16; ++r) { mx = fmaxf(mx, s0[r]); mx = fmaxf(mx, s1[r]); }
        mx = fmaxf(mx, __shfl_xor(mx, 32));
        const bool need = __any(mx > m_run + 8.f);   // defer-max THR=8
        if (need) {
          const float nm = fmaxf(m_run, mx);
          const float cr = __expf(m_run - nm);
          m_run = nm; l_run *= cr;
#pragma unroll
          for (int r = 0; r < 16; ++r) {
            const float crg = __shfl(cr, (r & 3) + 8 * (r >> 2) + 4 * hi);
#pragma unroll
            for (int db = 0; db < 4; ++db) acc[db][r] *= crg;
          }
        }
        float ts = 0.f;
#pragma unroll
        for (int r = 0; r < 16; ++r) {
          s0[r] = __expf(s0[r] - m_run); ts += s0[r];
          s1[r] = __expf(s1[r] - m_run); ts += s1[r];
        }
        ts += __shfl_xor(ts, 32);
        l_run += ts;

        // ---- P -> A-frags: cvt_pk pairs + xor-32 word swap
        bf16x8 pf[4];
#pragma unroll
        for (int ks = 0; ks < 4; ++ks) {
          const int o = (ks & 1) * 8;
          uint32_t w0, w1, w2, w3;
          if (ks < 2) {
            w0 = cvtpk(s0[o + 0], s0[o + 1]); w1 = cvtpk(s0[o + 4], s0[o + 5]);
            w2 = cvtpk(s0[o + 2], s0[o + 3]); w3 = cvtpk(s0[o + 6], s0[o + 7]);
          } else {
            w0 = cvtpk(s1[o + 0], s1[o + 1]); w1 = cvtpk(s1[o + 4], s1[o + 5]);
            w2 = cvtpk(s1[o + 2], s1[o + 3]); w3 = cvtpk(s1[o + 6], s1[o + 7]);
          }
          const uint32_t t0 = __shfl_xor(w0, 32), t1 = __shfl_xor(w1, 32);
          const uint32_t t2 = __shfl_xor(w2, 32), t3 = __shfl_xor(w3, 32);
          union { bf16x8 v; uint32_t u[4]; } P;
          P.u[0] = hi ? t1 : w0;    // j=0,1
          P.u[1] = hi ? t3 : w2;    // j=2,3
          P.u[2] = hi ? w1 : t0;    // j=4,5
          P.u[3] = hi ? w3 : t2;    // j=6,7
          pf[ks] = P.v;
        }

        // ---- PV: O[32q x 128d] += P[32q x 64k] * V[64k x 128d]
        const u16* VtC = (const u16*)(LB + 98304);
#pragma unroll
        for (int ks = 0; ks < 4; ++ks)
#pragma unroll
          for (int db = 0; db < 4; ++db) {
            const int row = db * 32 + l31;
            bf16x8 vf = *(const bf16x8*)&VtC[row * 128 + 8 * ((half * 8 + 2 * ks + hi) ^ (row & 7))];
            acc[db] = __builtin_amdgcn_mfma_f32_32x32x16_bf16(pf[ks], vf, acc[db], 0, 0, 0);
          }
      }

      __syncthreads();   // A: all reads of Kn[cur]/Vt done; gll(t+1)+Vregs drained
      if (havenext) {
        union { uint4 v; u16 u[8]; } A0, A1, B0, B1;
        A0.v = va0; A1.v = va1; B0.v = vb0; B1.v = vb1;
        char* vt = (char*)(LB + 98304);
        const int inb = (4 * vkp) & 15, cc = vkp >> 2;
#pragma unroll
        for (int i = 0; i < 8; ++i) {
          { const int d = vdc * 16 + i;
            uint32_t wv = (uint32_t)A0.u[i] | ((uint32_t)B0.u[i] << 16);
            *(uint32_t*)(vt + d * 256 + 16 * (cc ^ (d & 7)) + inb) = wv; }
          { const int d = vdc * 16 + 8 + i;
            uint32_t wv = (uint32_t)A1.u[i] | ((uint32_t)B1.u[i] << 16);
            *(uint32_t*)(vt + d * 256 + 16 * (cc ^ (d & 7)) + inb) = wv; }
        }
        __syncthreads();  // B: Vt(t+1) published
      }
    }

    // ---- merge k-halves (waves w and w+4 share rows) + write out
    float* mb = (float*)LB;                 // 64KB acc buffer (Kn area, reads done)
    float* ml = (float*)(LB + 65536);       // m,l per strip
    if (half == 1) {
#pragma unroll
      for (int db = 0; db < 4; ++db)
#pragma unroll
        for (int q4 = 0; q4 < 4; ++q4) {
          float4 v = make_float4(acc[db][q4 * 4 + 0], acc[db][q4 * 4 + 1],
                                 acc[db][q4 * 4 + 2], acc[db][q4 * 4 + 3]);
          *(float4*)&mb[strip * 4096 + db * 1024 + q4 * 256 + lane * 4] = v;
        }
      if (lane < 32) { ml[strip * 64 + lane] = m_run; ml[strip * 64 + 32 + lane] = l_run; }
    }
    __syncthreads();
    if (half == 0) {
      const float mp = ml[strip * 64 + l31];
      const float lp = ml[strip * 64 + 32 + l31];
      const float M  = fmaxf(m_run, mp);
      const float sA = __expf(m_run - M);
      const float sB = __expf(mp - M);
      const float inv = 1.0f / (l_run * sA + lp * sB);
      const float fAl = sA * inv, fBl = sB * inv;
      float fA[16], fB[16];
#pragma unroll
      for (int r = 0; r < 16; ++r) {
        const int cr_ = (r & 3) + 8 * (r >> 2) + 4 * hi;
        fA[r] = __shfl(fAl, cr_);
        fB[r] = __shfl(fBl, cr_);
      }
#pragma unroll
      for (int db = 0; db < 4; ++db)
#pragma unroll
        for (int q4 = 0; q4 < 4; ++q4) {
          float4 pv = *(const float4*)&mb[strip * 4096 + db * 1024 + q4 * 256 + lane * 4];
#pragma unroll
          for (int jj = 0; jj < 4; ++jj) {
            const int r = q4 * 4 + jj;
            const int cr_ = (r & 3) + 8 * (r >> 2) + 4 * hi;
            const float pvj = (jj == 0) ? pv.x : (jj == 1) ? pv.y : (jj == 2) ? pv.z : pv.w;
            out[((size_t)(tok0 + q0 + cr_) * Hz + h) * 128 + db * 32 + l31] =
                acc[db][r] * fA[r] + pvj * fB[r];
          }
        }
    }
    __syncthreads();   // before next pass re-stages LDS
  }
}

// ---------------------------------------------------------------- launch
extern "C" void kernel_launch(void* const* d_in, const int* in_sizes, int n_in,
                              void* d_out, int out_size, void* d_ws, size_t ws_size,
                              hipStream_t stream) {
  const float* q    = (const float*)d_in[0];
  const float* ckv  = (const float*)d_in[1];
  const float* rope = (const float*)d_in[2];
  const float* wup  = (const float*)d_in[3];
  float* out = (float*)d_out;

  u16* ckvb  = (u16*)d_ws;
  u16* wupb  = ckvb + (size_t)4096 * RANKz;
  u16* kvb   = wupb + (size_t)4096 * RANKz;
  u16* ropeb = kvb + (size_t)4096 * 4096;

  const int nvec = 4096 * RANKz / 4;       // 524288 float4 per matrix
  const int nrope = 4096 * 64 / 4;         // 65536 float4
  cvt_bf16_kernel<<<(2 * nvec + nrope) / 256, 256, 0, stream>>>(ckv, ckvb, wup, wupb, rope, ropeb, nvec, nvec);

  gemm_kv_bf16<<<1024, 256, 0, stream>>>(ckvb, wupb, kvb);

  mla_attn_mfma<<<256, 512, 0, stream>>>(q, kvb, ropeb, out);
}